// Round 1
// baseline (715.226 us; speedup 1.0000x reference)
//
#include <hip/hip_runtime.h>
#include <math.h>

// Problem constants
#define B_      16
#define CIN     256
#define HW_     4096          // 64x64
#define PLANES  256
#define G_      8
#define CG      32            // planes per group
#define EPSV    1e-5f

// ---------------------------------------------------------------------------
// Kernel 1: tmod[b][pix] = 1 + Wtm[0]*mask[b,0,pix] + Wtm[1]*mask[b,1,pix]
//           + zero the GN stats accumulator
// ---------------------------------------------------------------------------
__global__ __launch_bounds__(256) void k_tmod_zero(
    const float* __restrict__ mask, const float* __restrict__ Wtm,
    float* __restrict__ tmod, float* __restrict__ stats)
{
    int idx = blockIdx.x * 256 + threadIdx.x;   // 0 .. 65535
    float w0 = Wtm[0], w1 = Wtm[1];
    if (idx < B_ * HW_) {
        int b = idx >> 12, pix = idx & 4095;
        const float* mb = mask + (size_t)b * 2 * HW_;
        tmod[idx] = 1.0f + w0 * mb[pix] + w1 * mb[HW_ + pix];
    }
    if (blockIdx.x == 0 && threadIdx.x < 256) stats[threadIdx.x] = 0.0f;
}

// ---------------------------------------------------------------------------
// Kernel 2: fused conv1x1 GEMM.  C[512][4096] = Wall[512][256] @ x[b][256][4096]
//   rows   0..255 -> t   (times tmod factor)
//   rows 256..383 -> p
//   rows 384..511 -> g
// Tiling: BM=64, BN=128, BK=16, 256 threads, each thread 4x8 outputs.
// ---------------------------------------------------------------------------
__global__ __launch_bounds__(256) void k_conv1x1(
    const float* __restrict__ x,  const float* __restrict__ Wt,
    const float* __restrict__ Wp, const float* __restrict__ Wg,
    const float* __restrict__ tmod,
    float* __restrict__ tbuf, float* __restrict__ pbuf, float* __restrict__ gbuf)
{
    __shared__ float Wlds[16][64];
    __shared__ float xlds[16][128];

    int tid  = threadIdx.x;
    int pix0 = blockIdx.x * 128;
    int row0 = blockIdx.y * 64;
    int b    = blockIdx.z;
    int ty = tid >> 4, tx = tid & 15;

    float acc[4][8];
    #pragma unroll
    for (int i = 0; i < 4; ++i)
        #pragma unroll
        for (int j = 0; j < 8; ++j) acc[i][j] = 0.0f;

    // W staging assignment: thread -> (m = tid>>2, kq = (tid&3)*4)
    int m  = tid >> 2;
    int kq = (tid & 3) * 4;
    int wr = row0 + m;
    const float* wrow;
    if      (wr < 256) wrow = Wt + (size_t)wr * 256;
    else if (wr < 384) wrow = Wp + (size_t)(wr - 256) * 256;
    else               wrow = Wg + (size_t)(wr - 384) * 256;

    const float* xb = x + (size_t)b * CIN * HW_;
    int px = (tid & 31) * 4;
    int cc = tid >> 5;   // 0..7

    for (int kt = 0; kt < 16; ++kt) {
        int k0 = kt * 16;
        float4 wv = *(const float4*)(wrow + k0 + kq);
        Wlds[kq + 0][m] = wv.x;
        Wlds[kq + 1][m] = wv.y;
        Wlds[kq + 2][m] = wv.z;
        Wlds[kq + 3][m] = wv.w;
        #pragma unroll
        for (int it = 0; it < 2; ++it) {
            int c = k0 + cc + it * 8;
            float4 xv = *(const float4*)(xb + (size_t)c * HW_ + pix0 + px);
            *(float4*)(&xlds[cc + it * 8][px]) = xv;
        }
        __syncthreads();
        #pragma unroll
        for (int k = 0; k < 16; ++k) {
            float4 av = *(const float4*)(&Wlds[k][ty * 4]);
            float4 b0 = *(const float4*)(&xlds[k][tx * 8]);
            float4 b1 = *(const float4*)(&xlds[k][tx * 8 + 4]);
            float aa[4] = {av.x, av.y, av.z, av.w};
            float bb[8] = {b0.x, b0.y, b0.z, b0.w, b1.x, b1.y, b1.z, b1.w};
            #pragma unroll
            for (int i = 0; i < 4; ++i)
                #pragma unroll
                for (int j = 0; j < 8; ++j)
                    acc[i][j] = fmaf(aa[i], bb[j], acc[i][j]);
        }
        __syncthreads();
    }

    // epilogue
    #pragma unroll
    for (int i = 0; i < 4; ++i) {
        int r = row0 + ty * 4 + i;
        #pragma unroll
        for (int j = 0; j < 8; ++j) {
            int pix = pix0 + tx * 8 + j;
            float v = acc[i][j];
            if (r < 256) {
                tbuf[((size_t)b * 256 + r) * HW_ + pix] = v * tmod[b * HW_ + pix];
            } else if (r < 384) {
                pbuf[((size_t)b * 128 + (r - 256)) * HW_ + pix] = v;
            } else {
                gbuf[((size_t)b * 128 + (r - 384)) * HW_ + pix] = v;
            }
        }
    }
}

// ---------------------------------------------------------------------------
// Kernel 3: att[b][gi] = sum_{c,pix} P[b, gi*32+c, pix] * Gv[b, gi*32+c, pix]
//   gi 0..3 : raw p,g channels (gi*32 .. +31)
//   gi 4..7 : 3x3 maxpool of raw channels ((gi-4)*32 .. +31), computed on the fly
// ---------------------------------------------------------------------------
__global__ __launch_bounds__(256) void k_att(
    const float* __restrict__ pbuf, const float* __restrict__ gbuf,
    float* __restrict__ att)
{
    __shared__ float plds[HW_];
    __shared__ float glds[HW_];
    __shared__ float scr[8];
    int gi = blockIdx.x, b = blockIdx.y;
    int tid = threadIdx.x;
    float acc = 0.0f;

    if (gi < 4) {
        const float* pp = pbuf + ((size_t)b * 128 + gi * 32) * HW_;
        const float* gg = gbuf + ((size_t)b * 128 + gi * 32) * HW_;
        for (int i = tid; i < 32 * HW_; i += 256) acc += pp[i] * gg[i];
    } else {
        int cbase = (gi - 4) * 32;
        for (int c = 0; c < 32; ++c) {
            const float* pp = pbuf + ((size_t)b * 128 + cbase + c) * HW_;
            const float* gg = gbuf + ((size_t)b * 128 + cbase + c) * HW_;
            for (int i = tid; i < HW_; i += 256) { plds[i] = pp[i]; glds[i] = gg[i]; }
            __syncthreads();
            for (int i = tid; i < HW_; i += 256) {
                int h = i >> 6, w = i & 63;
                int h0 = max(h - 1, 0), h1 = min(h + 1, 63);
                int w0 = max(w - 1, 0), w1 = min(w + 1, 63);
                float mp = -3.0e38f, mg = -3.0e38f;
                for (int hh = h0; hh <= h1; ++hh)
                    for (int ww = w0; ww <= w1; ++ww) {
                        mp = fmaxf(mp, plds[hh * 64 + ww]);
                        mg = fmaxf(mg, glds[hh * 64 + ww]);
                    }
                acc += mp * mg;
            }
            __syncthreads();
        }
    }

    // block reduce (64-lane waves)
    #pragma unroll
    for (int off = 32; off > 0; off >>= 1) acc += __shfl_down(acc, off, 64);
    int lane = tid & 63, wid = tid >> 6;
    if (lane == 0) scr[wid] = acc;
    __syncthreads();
    if (tid == 0) att[b * 8 + gi] = scr[0] + scr[1] + scr[2] + scr[3];
}

// ---------------------------------------------------------------------------
// Kernel 4: in-place spatial softmax per (b, channel) row of tbuf
// ---------------------------------------------------------------------------
__global__ __launch_bounds__(256) void k_softmax(float* __restrict__ tbuf)
{
    __shared__ float row[HW_];
    __shared__ float scr[8];
    int r = blockIdx.x;            // b*256 + c
    float* tr = tbuf + (size_t)r * HW_;
    int tid = threadIdx.x;
    int lane = tid & 63, wid = tid >> 6;

    float mx = -3.0e38f;
    for (int i = tid; i < HW_; i += 256) {
        float v = tr[i]; row[i] = v; mx = fmaxf(mx, v);
    }
    #pragma unroll
    for (int off = 32; off > 0; off >>= 1) mx = fmaxf(mx, __shfl_down(mx, off, 64));
    if (lane == 0) scr[wid] = mx;
    __syncthreads();
    if (tid == 0) scr[0] = fmaxf(fmaxf(scr[0], scr[1]), fmaxf(scr[2], scr[3]));
    __syncthreads();
    float m = scr[0];
    __syncthreads();                 // protect scr before reuse

    float s = 0.0f;
    for (int i = tid; i < HW_; i += 256) {
        float e = __expf(row[i] - m);
        row[i] = e;
        s += e;
    }
    #pragma unroll
    for (int off = 32; off > 0; off >>= 1) s += __shfl_down(s, off, 64);
    if (lane == 0) scr[wid] = s;
    __syncthreads();
    if (tid == 0) scr[0] = scr[0] + scr[1] + scr[2] + scr[3];
    __syncthreads();
    float inv = 1.0f / scr[0];

    for (int i = tid; i < HW_; i += 256) tr[i] = row[i] * inv;
}

// ---------------------------------------------------------------------------
// Kernel 5: xz[b, gi*32+o, pix] = att[b,gi] * sum_i Wz[gi,o,i] * ts[b, gi*32+i, pix]
// in place over tbuf (block stages its full input tile in LDS first).
// Also accumulates per-(b,gi) sum / sumsq into stats via atomics.
// ---------------------------------------------------------------------------
__global__ __launch_bounds__(256) void k_xz(
    float* __restrict__ tbuf, const float* __restrict__ Wz,
    const float* __restrict__ att, float* __restrict__ stats)
{
    __shared__ float ts[32][256];
    __shared__ float wz[32][32];
    __shared__ float scr[8];
    int pt  = blockIdx.x;   // 0..15   (256-pixel tile)
    int gi  = blockIdx.y;   // 0..7
    int b   = blockIdx.z;   // 0..15
    int tid = threadIdx.x;
    int pix0 = pt * 256;

    float* base = tbuf + ((size_t)b * 256 + gi * 32) * HW_;
    #pragma unroll 4
    for (int i = 0; i < 32; ++i) ts[i][tid] = base[(size_t)i * HW_ + pix0 + tid];
    const float* wzg = Wz + gi * 32 * 32;
    #pragma unroll
    for (int i = 0; i < 4; ++i) {
        int idx = tid + i * 256;
        wz[idx >> 5][idx & 31] = wzg[idx];
    }
    __syncthreads();

    float a = att[b * 8 + gi];
    float v[32];
    #pragma unroll
    for (int i = 0; i < 32; ++i) v[i] = ts[i][tid];

    float s1 = 0.0f, s2 = 0.0f;
    for (int o = 0; o < 32; ++o) {
        float acc = 0.0f;
        #pragma unroll
        for (int i = 0; i < 32; ++i) acc = fmaf(wz[o][i], v[i], acc);
        acc *= a;
        base[(size_t)o * HW_ + pix0 + tid] = acc;
        s1 += acc;
        s2 = fmaf(acc, acc, s2);
    }

    #pragma unroll
    for (int off = 32; off > 0; off >>= 1) {
        s1 += __shfl_down(s1, off, 64);
        s2 += __shfl_down(s2, off, 64);
    }
    int lane = tid & 63, wid = tid >> 6;
    if (lane == 0) { scr[wid] = s1; scr[4 + wid] = s2; }
    __syncthreads();
    if (tid == 0) {
        float S1 = scr[0] + scr[1] + scr[2] + scr[3];
        float S2 = scr[4] + scr[5] + scr[6] + scr[7];
        atomicAdd(&stats[(b * 8 + gi) * 2 + 0], S1);
        atomicAdd(&stats[(b * 8 + gi) * 2 + 1], S2);
    }
}

// ---------------------------------------------------------------------------
// Kernel 6: GroupNorm finalize + affine + residual
// ---------------------------------------------------------------------------
__global__ __launch_bounds__(256) void k_finalize(
    const float* __restrict__ xzbuf, const float* __restrict__ x,
    const float* __restrict__ stats, const float* __restrict__ gamma,
    const float* __restrict__ beta, float* __restrict__ out)
{
    size_t idx = (size_t)blockIdx.x * 256 + threadIdx.x;
    int c  = (int)((idx >> 12) & 255);
    int bg = (int)(idx >> 17);              // b*8 + gi
    float s1 = stats[bg * 2], s2 = stats[bg * 2 + 1];
    const float invN = 1.0f / 131072.0f;
    float mu  = s1 * invN;
    float var = s2 * invN - mu * mu;
    float rs  = rsqrtf(var + EPSV);
    out[idx] = (xzbuf[idx] - mu) * rs * gamma[c] + beta[c] + x[idx];
}

// ---------------------------------------------------------------------------
extern "C" void kernel_launch(void* const* d_in, const int* in_sizes, int n_in,
                              void* d_out, int out_size, void* d_ws, size_t ws_size,
                              hipStream_t stream)
{
    const float* x     = (const float*)d_in[0];
    const float* mask  = (const float*)d_in[1];
    const float* Wt    = (const float*)d_in[2];
    const float* Wtm   = (const float*)d_in[3];
    const float* Wp    = (const float*)d_in[4];
    const float* Wg    = (const float*)d_in[5];
    const float* Wz    = (const float*)d_in[6];
    const float* gamma = (const float*)d_in[7];
    const float* beta  = (const float*)d_in[8];
    float* out = (float*)d_out;

    // workspace layout (floats):
    //   tbuf  : 16*256*4096 = 16,777,216   (t -> softmax(ts) -> xz, in place)
    //   pbuf  : 16*128*4096 =  8,388,608
    //   gbuf  : 16*128*4096 =  8,388,608
    //   tmod  : 65,536
    //   att   : 128
    //   stats : 256
    // total ~128.3 MiB
    float* ws    = (float*)d_ws;
    float* tbuf  = ws;
    float* pbuf  = tbuf + (size_t)16 * 256 * 4096;
    float* gbuf  = pbuf + (size_t)16 * 128 * 4096;
    float* tmod  = gbuf + (size_t)16 * 128 * 4096;
    float* att   = tmod + 65536;
    float* stats = att + 128;

    k_tmod_zero<<<256, 256, 0, stream>>>(mask, Wtm, tmod, stats);
    k_conv1x1 <<<dim3(32, 8, 16), 256, 0, stream>>>(x, Wt, Wp, Wg, tmod, tbuf, pbuf, gbuf);
    k_att     <<<dim3(8, 16),     256, 0, stream>>>(pbuf, gbuf, att);
    k_softmax <<<4096,            256, 0, stream>>>(tbuf);
    k_xz      <<<dim3(16, 8, 16), 256, 0, stream>>>(tbuf, Wz, att, stats);
    k_finalize<<<65536,           256, 0, stream>>>(tbuf, x, stats, gamma, beta, out);
}

// Round 2
// 389.891 us; speedup vs baseline: 1.8344x; 1.8344x over previous
//
#include <hip/hip_runtime.h>
#include <math.h>

// Problem constants
#define B_      16
#define CIN     256
#define HW_     4096          // 64x64
#define PLANES  256
#define G_      8
#define CG      32            // planes per group
#define EPSV    1e-5f

// ---------------------------------------------------------------------------
// Kernel 1: tmod[b][pix] = 1 + Wtm[0]*mask[b,0,pix] + Wtm[1]*mask[b,1,pix]
//           + zero the att + GN-stats accumulators
// ---------------------------------------------------------------------------
__global__ __launch_bounds__(256) void k_tmod_zero(
    const float* __restrict__ mask, const float* __restrict__ Wtm,
    float* __restrict__ tmod, float* __restrict__ att, float* __restrict__ stats)
{
    int idx = blockIdx.x * 256 + threadIdx.x;   // 0 .. 65535
    float w0 = Wtm[0], w1 = Wtm[1];
    if (idx < B_ * HW_) {
        int b = idx >> 12, pix = idx & 4095;
        const float* mb = mask + (size_t)b * 2 * HW_;
        tmod[idx] = 1.0f + w0 * mb[pix] + w1 * mb[HW_ + pix];
    }
    if (blockIdx.x == 0) {
        if (threadIdx.x < 128) att[threadIdx.x] = 0.0f;
        stats[threadIdx.x] = 0.0f;
    }
}

// ---------------------------------------------------------------------------
// Kernel 2: fused conv1x1 GEMM.  C[512][4096] = Wall[512][256] @ x[b][256][4096]
//   rows   0..255 -> t   (times tmod factor)
//   rows 256..383 -> p
//   rows 384..511 -> g
// Tiling: BM=64, BN=128, BK=16, 256 threads, each thread 4x8 outputs.
// ---------------------------------------------------------------------------
__global__ __launch_bounds__(256) void k_conv1x1(
    const float* __restrict__ x,  const float* __restrict__ Wt,
    const float* __restrict__ Wp, const float* __restrict__ Wg,
    const float* __restrict__ tmod,
    float* __restrict__ tbuf, float* __restrict__ pbuf, float* __restrict__ gbuf)
{
    __shared__ float Wlds[16][64];
    __shared__ float xlds[16][128];

    int tid  = threadIdx.x;
    int pix0 = blockIdx.x * 128;
    int row0 = blockIdx.y * 64;
    int b    = blockIdx.z;
    int ty = tid >> 4, tx = tid & 15;

    float acc[4][8];
    #pragma unroll
    for (int i = 0; i < 4; ++i)
        #pragma unroll
        for (int j = 0; j < 8; ++j) acc[i][j] = 0.0f;

    // W staging assignment: thread -> (m = tid>>2, kq = (tid&3)*4)
    int m  = tid >> 2;
    int kq = (tid & 3) * 4;
    int wr = row0 + m;
    const float* wrow;
    if      (wr < 256) wrow = Wt + (size_t)wr * 256;
    else if (wr < 384) wrow = Wp + (size_t)(wr - 256) * 256;
    else               wrow = Wg + (size_t)(wr - 384) * 256;

    const float* xb = x + (size_t)b * CIN * HW_;
    int px = (tid & 31) * 4;
    int cc = tid >> 5;   // 0..7

    for (int kt = 0; kt < 16; ++kt) {
        int k0 = kt * 16;
        float4 wv = *(const float4*)(wrow + k0 + kq);
        Wlds[kq + 0][m] = wv.x;
        Wlds[kq + 1][m] = wv.y;
        Wlds[kq + 2][m] = wv.z;
        Wlds[kq + 3][m] = wv.w;
        #pragma unroll
        for (int it = 0; it < 2; ++it) {
            int c = k0 + cc + it * 8;
            float4 xv = *(const float4*)(xb + (size_t)c * HW_ + pix0 + px);
            *(float4*)(&xlds[cc + it * 8][px]) = xv;
        }
        __syncthreads();
        #pragma unroll
        for (int k = 0; k < 16; ++k) {
            float4 av = *(const float4*)(&Wlds[k][ty * 4]);
            float4 b0 = *(const float4*)(&xlds[k][tx * 8]);
            float4 b1 = *(const float4*)(&xlds[k][tx * 8 + 4]);
            float aa[4] = {av.x, av.y, av.z, av.w};
            float bb[8] = {b0.x, b0.y, b0.z, b0.w, b1.x, b1.y, b1.z, b1.w};
            #pragma unroll
            for (int i = 0; i < 4; ++i)
                #pragma unroll
                for (int j = 0; j < 8; ++j)
                    acc[i][j] = fmaf(aa[i], bb[j], acc[i][j]);
        }
        __syncthreads();
    }

    // epilogue
    #pragma unroll
    for (int i = 0; i < 4; ++i) {
        int r = row0 + ty * 4 + i;
        #pragma unroll
        for (int j = 0; j < 8; ++j) {
            int pix = pix0 + tx * 8 + j;
            float v = acc[i][j];
            if (r < 256) {
                tbuf[((size_t)b * 256 + r) * HW_ + pix] = v * tmod[b * HW_ + pix];
            } else if (r < 384) {
                pbuf[((size_t)b * 128 + (r - 256)) * HW_ + pix] = v;
            } else {
                gbuf[((size_t)b * 128 + (r - 384)) * HW_ + pix] = v;
            }
        }
    }
}

// ---------------------------------------------------------------------------
// Kernel 3: attention dot.  One block per (b, gi<4, channel c).
//   Loads p[b, gi*32+c, :] and g[b, gi*32+c, :] into LDS once, computes
//     raw contribution  -> atomicAdd att[b*8 + gi]
//     3x3-maxpool contribution -> atomicAdd att[b*8 + gi + 4]
// ---------------------------------------------------------------------------
__global__ __launch_bounds__(256) void k_att(
    const float* __restrict__ pbuf, const float* __restrict__ gbuf,
    float* __restrict__ att)
{
    __shared__ float plds[HW_];
    __shared__ float glds[HW_];
    __shared__ float scr[8];
    int c  = blockIdx.x;   // 0..31
    int gi = blockIdx.y;   // 0..3
    int b  = blockIdx.z;   // 0..15
    int tid = threadIdx.x;

    const float* pp = pbuf + ((size_t)b * 128 + gi * 32 + c) * HW_;
    const float* gg = gbuf + ((size_t)b * 128 + gi * 32 + c) * HW_;

    // stage + raw dot (float4, 4 iters of 1024 floats)
    float racc = 0.0f;
    #pragma unroll
    for (int it = 0; it < 4; ++it) {
        int i = it * 1024 + tid * 4;
        float4 pv = *(const float4*)(pp + i);
        float4 gv = *(const float4*)(gg + i);
        *(float4*)(&plds[i]) = pv;
        *(float4*)(&glds[i]) = gv;
        racc += pv.x * gv.x + pv.y * gv.y + pv.z * gv.z + pv.w * gv.w;
    }
    __syncthreads();

    // pooled dot
    float pacc = 0.0f;
    #pragma unroll 4
    for (int i = tid; i < HW_; i += 256) {
        int h = i >> 6, w = i & 63;
        int h0 = max(h - 1, 0), h1 = min(h + 1, 63);
        int w0 = max(w - 1, 0), w1 = min(w + 1, 63);
        float mp = -3.0e38f, mg = -3.0e38f;
        for (int hh = h0; hh <= h1; ++hh)
            for (int ww = w0; ww <= w1; ++ww) {
                mp = fmaxf(mp, plds[hh * 64 + ww]);
                mg = fmaxf(mg, glds[hh * 64 + ww]);
            }
        pacc += mp * mg;
    }

    // block reduce both sums (64-lane waves)
    #pragma unroll
    for (int off = 32; off > 0; off >>= 1) {
        racc += __shfl_down(racc, off, 64);
        pacc += __shfl_down(pacc, off, 64);
    }
    int lane = tid & 63, wid = tid >> 6;
    if (lane == 0) { scr[wid] = racc; scr[4 + wid] = pacc; }
    __syncthreads();
    if (tid == 0) {
        atomicAdd(&att[b * 8 + gi],     scr[0] + scr[1] + scr[2] + scr[3]);
        atomicAdd(&att[b * 8 + gi + 4], scr[4] + scr[5] + scr[6] + scr[7]);
    }
}

// ---------------------------------------------------------------------------
// Kernel 4: in-place spatial softmax per (b, channel) row of tbuf
// ---------------------------------------------------------------------------
__global__ __launch_bounds__(256) void k_softmax(float* __restrict__ tbuf)
{
    __shared__ float row[HW_];
    __shared__ float scr[8];
    int r = blockIdx.x;            // b*256 + c
    float* tr = tbuf + (size_t)r * HW_;
    int tid = threadIdx.x;
    int lane = tid & 63, wid = tid >> 6;

    float mx = -3.0e38f;
    for (int i = tid; i < HW_; i += 256) {
        float v = tr[i]; row[i] = v; mx = fmaxf(mx, v);
    }
    #pragma unroll
    for (int off = 32; off > 0; off >>= 1) mx = fmaxf(mx, __shfl_down(mx, off, 64));
    if (lane == 0) scr[wid] = mx;
    __syncthreads();
    if (tid == 0) scr[0] = fmaxf(fmaxf(scr[0], scr[1]), fmaxf(scr[2], scr[3]));
    __syncthreads();
    float m = scr[0];
    __syncthreads();                 // protect scr before reuse

    float s = 0.0f;
    for (int i = tid; i < HW_; i += 256) {
        float e = __expf(row[i] - m);
        row[i] = e;
        s += e;
    }
    #pragma unroll
    for (int off = 32; off > 0; off >>= 1) s += __shfl_down(s, off, 64);
    if (lane == 0) scr[wid] = s;
    __syncthreads();
    if (tid == 0) scr[0] = scr[0] + scr[1] + scr[2] + scr[3];
    __syncthreads();
    float inv = 1.0f / scr[0];

    for (int i = tid; i < HW_; i += 256) tr[i] = row[i] * inv;
}

// ---------------------------------------------------------------------------
// Kernel 5: xz[b, gi*32+o, pix] = att[b,gi] * sum_i Wz[gi,o,i] * ts[b, gi*32+i, pix]
// in place over tbuf (block stages its full input tile in LDS first).
// Also accumulates per-(b,gi) sum / sumsq into stats via atomics.
// ---------------------------------------------------------------------------
__global__ __launch_bounds__(256) void k_xz(
    float* __restrict__ tbuf, const float* __restrict__ Wz,
    const float* __restrict__ att, float* __restrict__ stats)
{
    __shared__ float ts[32][256];
    __shared__ float wz[32][32];
    __shared__ float scr[8];
    int pt  = blockIdx.x;   // 0..15   (256-pixel tile)
    int gi  = blockIdx.y;   // 0..7
    int b   = blockIdx.z;   // 0..15
    int tid = threadIdx.x;
    int pix0 = pt * 256;

    float* base = tbuf + ((size_t)b * 256 + gi * 32) * HW_;
    #pragma unroll 4
    for (int i = 0; i < 32; ++i) ts[i][tid] = base[(size_t)i * HW_ + pix0 + tid];
    const float* wzg = Wz + gi * 32 * 32;
    #pragma unroll
    for (int i = 0; i < 4; ++i) {
        int idx = tid + i * 256;
        wz[idx >> 5][idx & 31] = wzg[idx];
    }
    __syncthreads();

    float a = att[b * 8 + gi];
    float v[32];
    #pragma unroll
    for (int i = 0; i < 32; ++i) v[i] = ts[i][tid];

    float s1 = 0.0f, s2 = 0.0f;
    for (int o = 0; o < 32; ++o) {
        float acc = 0.0f;
        #pragma unroll
        for (int i = 0; i < 32; ++i) acc = fmaf(wz[o][i], v[i], acc);
        acc *= a;
        base[(size_t)o * HW_ + pix0 + tid] = acc;
        s1 += acc;
        s2 = fmaf(acc, acc, s2);
    }

    #pragma unroll
    for (int off = 32; off > 0; off >>= 1) {
        s1 += __shfl_down(s1, off, 64);
        s2 += __shfl_down(s2, off, 64);
    }
    int lane = tid & 63, wid = tid >> 6;
    if (lane == 0) { scr[wid] = s1; scr[4 + wid] = s2; }
    __syncthreads();
    if (tid == 0) {
        float S1 = scr[0] + scr[1] + scr[2] + scr[3];
        float S2 = scr[4] + scr[5] + scr[6] + scr[7];
        atomicAdd(&stats[(b * 8 + gi) * 2 + 0], S1);
        atomicAdd(&stats[(b * 8 + gi) * 2 + 1], S2);
    }
}

// ---------------------------------------------------------------------------
// Kernel 6: GroupNorm finalize + affine + residual
// ---------------------------------------------------------------------------
__global__ __launch_bounds__(256) void k_finalize(
    const float* __restrict__ xzbuf, const float* __restrict__ x,
    const float* __restrict__ stats, const float* __restrict__ gamma,
    const float* __restrict__ beta, float* __restrict__ out)
{
    size_t idx = (size_t)blockIdx.x * 256 + threadIdx.x;
    int c  = (int)((idx >> 12) & 255);
    int bg = (int)(idx >> 17);              // b*8 + gi
    float s1 = stats[bg * 2], s2 = stats[bg * 2 + 1];
    const float invN = 1.0f / 131072.0f;
    float mu  = s1 * invN;
    float var = s2 * invN - mu * mu;
    float rs  = rsqrtf(var + EPSV);
    out[idx] = (xzbuf[idx] - mu) * rs * gamma[c] + beta[c] + x[idx];
}

// ---------------------------------------------------------------------------
extern "C" void kernel_launch(void* const* d_in, const int* in_sizes, int n_in,
                              void* d_out, int out_size, void* d_ws, size_t ws_size,
                              hipStream_t stream)
{
    const float* x     = (const float*)d_in[0];
    const float* mask  = (const float*)d_in[1];
    const float* Wt    = (const float*)d_in[2];
    const float* Wtm   = (const float*)d_in[3];
    const float* Wp    = (const float*)d_in[4];
    const float* Wg    = (const float*)d_in[5];
    const float* Wz    = (const float*)d_in[6];
    const float* gamma = (const float*)d_in[7];
    const float* beta  = (const float*)d_in[8];
    float* out = (float*)d_out;

    // workspace layout (floats):
    //   tbuf  : 16*256*4096 = 16,777,216   (t -> softmax(ts) -> xz, in place)
    //   pbuf  : 16*128*4096 =  8,388,608
    //   gbuf  : 16*128*4096 =  8,388,608
    //   tmod  : 65,536
    //   att   : 128
    //   stats : 256
    // total ~128.3 MiB
    float* ws    = (float*)d_ws;
    float* tbuf  = ws;
    float* pbuf  = tbuf + (size_t)16 * 256 * 4096;
    float* gbuf  = pbuf + (size_t)16 * 128 * 4096;
    float* tmod  = gbuf + (size_t)16 * 128 * 4096;
    float* att   = tmod + 65536;
    float* stats = att + 128;

    k_tmod_zero<<<256, 256, 0, stream>>>(mask, Wtm, tmod, att, stats);
    k_conv1x1 <<<dim3(32, 8, 16), 256, 0, stream>>>(x, Wt, Wp, Wg, tmod, tbuf, pbuf, gbuf);
    k_att     <<<dim3(32, 4, 16), 256, 0, stream>>>(pbuf, gbuf, att);
    k_softmax <<<4096,            256, 0, stream>>>(tbuf);
    k_xz      <<<dim3(16, 8, 16), 256, 0, stream>>>(tbuf, Wz, att, stats);
    k_finalize<<<65536,           256, 0, stream>>>(tbuf, x, stats, gamma, beta, out);
}

// Round 6
// 340.114 us; speedup vs baseline: 2.1029x; 1.1464x over previous
//
#include <hip/hip_runtime.h>
#include <math.h>

#define B_      16
#define CIN     256
#define HW_     4096          // 64x64
#define PLANES  256
#define G_      8
#define EPSV    1e-5f

typedef unsigned short u16;
typedef __attribute__((ext_vector_type(8))) short short8;   // 8 bf16 (4 VGPRs)
typedef __attribute__((ext_vector_type(4))) float f32x4;    // MFMA acc

__device__ inline u16 f2bf(float f) {
    union { float f; unsigned u; } v; v.f = f;
    unsigned u = v.u;
    return (u16)((u + 0x7fffu + ((u >> 16) & 1u)) >> 16);   // RNE
}
__device__ inline float bf2f(u16 h) {
    union { unsigned u; float f; } v; v.u = ((unsigned)h) << 16;
    return v.f;
}

// ---------------------------------------------------------------------------
// Kernel 0a: pack Wt|Wp|Wg (512x256 f32) into MFMA A-fragment order, split
// into bf16 hi + lo (w = hi + lo, exact to ~2^-16 rel).
// slot (rt 0..3, kt 0..7, mb 0..7, lane 0..63, j 0..7):
//   row = rt*128 + mb*16 + (lane&15); k = kt*32 + (lane>>4)*8 + j
// ---------------------------------------------------------------------------
__global__ __launch_bounds__(256) void k_packA(
    const float* __restrict__ Wt, const float* __restrict__ Wp,
    const float* __restrict__ Wg,
    u16* __restrict__ pAhi, u16* __restrict__ pAlo)
{
    int t = blockIdx.x * 256 + threadIdx.x;      // 0..16383
    int lane = t & 63;
    int mb   = (t >> 6) & 7;
    int kt   = (t >> 9) & 7;
    int rt   = (t >> 12) & 3;
    int row = rt * 128 + mb * 16 + (lane & 15);
    int k0  = kt * 32 + (lane >> 4) * 8;
    const float* src;
    if      (row < 256) src = Wt + (size_t)row * 256;
    else if (row < 384) src = Wp + (size_t)(row - 256) * 256;
    else                src = Wg + (size_t)(row - 384) * 256;
    u16 hv[8], lv[8];
    #pragma unroll
    for (int j = 0; j < 8; ++j) {
        float w = src[k0 + j];
        u16 h = f2bf(w);
        hv[j] = h;
        lv[j] = f2bf(w - bf2f(h));
    }
    *(short8*)(pAhi + (size_t)t * 8) = *(short8*)hv;
    *(short8*)(pAlo + (size_t)t * 8) = *(short8*)lv;
}

// ---------------------------------------------------------------------------
// Kernel 0b: transpose x[b0+bz][256][4096] f32 -> xThi/xTlo[bz][4096][256]
// bf16 hi/lo split.  Quarter-batch (bz 0..3) per pass.
// ---------------------------------------------------------------------------
__global__ __launch_bounds__(256) void k_transpose(
    const float* __restrict__ x, u16* __restrict__ xThi,
    u16* __restrict__ xTlo, int b0)
{
    __shared__ float tile[32][129];
    int tid = threadIdx.x;
    int px0 = blockIdx.x * 128;
    int c0  = blockIdx.y * 32;
    int bz  = blockIdx.z;
    int bg  = b0 + bz;

    #pragma unroll
    for (int it = 0; it < 16; ++it) {
        int flat = it * 256 + tid;
        int c_l = flat >> 7, p_l = flat & 127;
        tile[c_l][p_l] = x[((size_t)bg * 256 + c0 + c_l) * 4096 + px0 + p_l];
    }
    __syncthreads();
    #pragma unroll
    for (int it = 0; it < 8; ++it) {
        int flat = it * 256 + tid;          // 0..2047
        int p_l = flat >> 4;
        int c_l = (flat & 15) * 2;
        float v0 = tile[c_l][p_l], v1 = tile[c_l + 1][p_l];
        u16 h0 = f2bf(v0), h1 = f2bf(v1);
        u16 l0 = f2bf(v0 - bf2f(h0)), l1 = f2bf(v1 - bf2f(h1));
        size_t o = ((size_t)bz * 4096 + px0 + p_l) * 256 + c0 + c_l;
        u16 ho[2] = { h0, h1 };
        u16 lo[2] = { l0, l1 };
        *(unsigned*)(xThi + o) = *(unsigned*)ho;
        *(unsigned*)(xTlo + o) = *(unsigned*)lo;
    }
}

// ---------------------------------------------------------------------------
// Kernel 1: tmod + zero att/stats
// ---------------------------------------------------------------------------
__global__ __launch_bounds__(256) void k_tmod_zero(
    const float* __restrict__ mask, const float* __restrict__ Wtm,
    float* __restrict__ tmod, float* __restrict__ att, float* __restrict__ stats)
{
    int idx = blockIdx.x * 256 + threadIdx.x;
    float w0 = Wtm[0], w1 = Wtm[1];
    if (idx < B_ * HW_) {
        int b = idx >> 12, pix = idx & 4095;
        const float* mb = mask + (size_t)b * 2 * HW_;
        tmod[idx] = 1.0f + w0 * mb[pix] + w1 * mb[HW_ + pix];
    }
    if (blockIdx.x == 0) {
        if (threadIdx.x < 128) att[threadIdx.x] = 0.0f;
        stats[threadIdx.x] = 0.0f;
    }
}

// ---------------------------------------------------------------------------
// Kernel 2: MFMA GEMM, quarter batch (4 images), two modes:
//   mode 0 (t rows 0..255):  1 pass  Whi*xhi          -> f32 tbuf (* tmod)
//   mode 1 (p/g rows 256..511): 3 passes Whi*xhi + Wlo*xhi + Whi*xlo
//                             (f32-exact)             -> f32 pbufq/gbufq
// Block: 128 rows x 128 px, 4 waves (2x2).  64 KB LDS B-panel, XOR-swizzled.
// ---------------------------------------------------------------------------
#define STAGE(SRC)                                                            \
    _Pragma("unroll")                                                         \
    for (int it = 0; it < 16; ++it) {                                         \
        int cidx = it * 256 + tid;                                            \
        int px   = cidx >> 5;                                                 \
        int boff = (cidx & 31) << 4;                                          \
        short8 v = *(const short8*)((SRC) + (size_t)px * 512 + boff);         \
        *(short8*)(Blds + px * 512 + (boff ^ ((px & 7) << 4))) = v;           \
    }

#define MFMA_PASS(ASRC)                                                       \
    _Pragma("unroll")                                                         \
    for (int kt = 0; kt < 8; ++kt) {                                          \
        short8 a[4], bb[4];                                                   \
        _Pragma("unroll")                                                     \
        for (int m = 0; m < 4; ++m)                                           \
            a[m] = *(const short8*)((ASRC) +                                  \
                ((((size_t)(rt * 8 + kt) * 8) + wm * 4 + m) * 64 + lane) * 8);\
        int off = ((kt * 64) + ((lane >> 4) << 4)) ^ ((lane & 7) << 4);       \
        _Pragma("unroll")                                                     \
        for (int n = 0; n < 4; ++n) {                                         \
            int px = wn * 64 + n * 16 + (lane & 15);                          \
            bb[n] = *(const short8*)(Blds + px * 512 + off);                  \
        }                                                                     \
        _Pragma("unroll")                                                     \
        for (int m = 0; m < 4; ++m)                                           \
            _Pragma("unroll")                                                 \
            for (int n = 0; n < 4; ++n)                                       \
                acc[m][n] = __builtin_amdgcn_mfma_f32_16x16x32_bf16(          \
                    a[m], bb[n], acc[m][n], 0, 0, 0);                         \
    }

__global__ __launch_bounds__(256) void k_mm(
    const u16* __restrict__ xThi, const u16* __restrict__ xTlo,
    const u16* __restrict__ pAhi, const u16* __restrict__ pAlo,
    const float* __restrict__ tmod,
    float* __restrict__ tbuf, float* __restrict__ pbufq, float* __restrict__ gbufq,
    int b0, int mode)
{
    __shared__ short8 BldsV[4096];           // 64 KB
    char* Blds = (char*)BldsV;
    int tid = threadIdx.x, lane = tid & 63, wid = tid >> 6;
    int wm = wid >> 1, wn = wid & 1;
    int pix0 = blockIdx.x * 128;
    int by   = blockIdx.y;                   // 0..1
    int rt   = (mode ? 2 : 0) + by;          // global 128-row tile index
    int bz = blockIdx.z, bg = b0 + bz;

    const char* srcHi = (const char*)(xThi + ((size_t)bz * 4096 + pix0) * 256);
    const char* srcLo = (const char*)(xTlo + ((size_t)bz * 4096 + pix0) * 256);

    f32x4 acc[4][4];
    #pragma unroll
    for (int m = 0; m < 4; ++m)
        #pragma unroll
        for (int n = 0; n < 4; ++n) acc[m][n] = (f32x4)0.0f;

    STAGE(srcHi);
    __syncthreads();
    MFMA_PASS(pAhi);
    if (mode) {
        MFMA_PASS(pAlo);
        __syncthreads();     // all waves done reading hi panel
        STAGE(srcLo);
        __syncthreads();
        MFMA_PASS(pAhi);
    }

    // ---- epilogue: D row = (lane>>4)*4 + r (M), col = lane&15 (N) ----
    int colb = pix0 + wn * 64;
    if (mode == 0) {
        int rowb = by * 128 + wm * 64;       // 0..255 within t
        float tm[4];
        #pragma unroll
        for (int n = 0; n < 4; ++n) tm[n] = tmod[bg * 4096 + colb + n * 16 + (lane & 15)];
        #pragma unroll
        for (int m = 0; m < 4; ++m)
            #pragma unroll
            for (int n = 0; n < 4; ++n)
                #pragma unroll
                for (int r = 0; r < 4; ++r) {
                    int row = rowb + m * 16 + (lane >> 4) * 4 + r;
                    int col = colb + n * 16 + (lane & 15);
                    tbuf[((size_t)bg * 256 + row) * 4096 + col] = acc[m][n][r] * tm[n];
                }
    } else {
        float* dst = (by == 0) ? pbufq : gbufq;   // by0: p rows, by1: g rows
        int rowb = wm * 64;                  // 0..127 within p or g
        #pragma unroll
        for (int m = 0; m < 4; ++m)
            #pragma unroll
            for (int n = 0; n < 4; ++n)
                #pragma unroll
                for (int r = 0; r < 4; ++r) {
                    int row = rowb + m * 16 + (lane >> 4) * 4 + r;
                    int col = colb + n * 16 + (lane & 15);
                    dst[((size_t)bz * 128 + row) * 4096 + col] = acc[m][n][r];
                }
    }
}

// ---------------------------------------------------------------------------
// Kernel 3: attention dot (f32), quarter batch.  Block per (c, gi, bz).
//   raw contribution  -> atomicAdd att[(b0+bz)*8 + gi]
//   3x3-maxpool contribution -> atomicAdd att[(b0+bz)*8 + gi + 4]
// ---------------------------------------------------------------------------
__global__ __launch_bounds__(256) void k_att(
    const float* __restrict__ pbufq, const float* __restrict__ gbufq,
    float* __restrict__ att, int b0)
{
    __shared__ float plds[HW_];
    __shared__ float glds[HW_];
    __shared__ float scr[8];
    int c  = blockIdx.x;   // 0..31
    int gi = blockIdx.y;   // 0..3
    int bz = blockIdx.z;   // 0..3
    int tid = threadIdx.x;

    const float* pp = pbufq + ((size_t)bz * 128 + gi * 32 + c) * HW_;
    const float* gg = gbufq + ((size_t)bz * 128 + gi * 32 + c) * HW_;

    float racc = 0.0f;
    #pragma unroll
    for (int it = 0; it < 4; ++it) {
        int i = it * 1024 + tid * 4;
        float4 pv = *(const float4*)(pp + i);
        float4 gv = *(const float4*)(gg + i);
        *(float4*)(&plds[i]) = pv;
        *(float4*)(&glds[i]) = gv;
        racc += pv.x * gv.x + pv.y * gv.y + pv.z * gv.z + pv.w * gv.w;
    }
    __syncthreads();

    float pacc = 0.0f;
    #pragma unroll 4
    for (int i = tid; i < HW_; i += 256) {
        int h = i >> 6, w = i & 63;
        int h0 = max(h - 1, 0), h1 = min(h + 1, 63);
        int w0 = max(w - 1, 0), w1 = min(w + 1, 63);
        float mp = -3.0e38f, mg = -3.0e38f;
        for (int hh = h0; hh <= h1; ++hh)
            for (int ww = w0; ww <= w1; ++ww) {
                mp = fmaxf(mp, plds[hh * 64 + ww]);
                mg = fmaxf(mg, glds[hh * 64 + ww]);
            }
        pacc += mp * mg;
    }

    #pragma unroll
    for (int off = 32; off > 0; off >>= 1) {
        racc += __shfl_down(racc, off, 64);
        pacc += __shfl_down(pacc, off, 64);
    }
    int lane = tid & 63, wid = tid >> 6;
    if (lane == 0) { scr[wid] = racc; scr[4 + wid] = pacc; }
    __syncthreads();
    if (tid == 0) {
        int bg = b0 + bz;
        atomicAdd(&att[bg * 8 + gi],     scr[0] + scr[1] + scr[2] + scr[3]);
        atomicAdd(&att[bg * 8 + gi + 4], scr[4] + scr[5] + scr[6] + scr[7]);
    }
}

// ---------------------------------------------------------------------------
// Kernel 4: in-place spatial softmax per (b, channel) row of tbuf (f32)
// ---------------------------------------------------------------------------
__global__ __launch_bounds__(256) void k_softmax(float* __restrict__ tbuf)
{
    __shared__ float row[HW_];
    __shared__ float scr[8];
    int r = blockIdx.x;            // b*256 + c
    float* tr = tbuf + (size_t)r * HW_;
    int tid = threadIdx.x;
    int lane = tid & 63, wid = tid >> 6;

    float mx = -3.0e38f;
    for (int i = tid; i < HW_; i += 256) {
        float v = tr[i]; row[i] = v; mx = fmaxf(mx, v);
    }
    #pragma unroll
    for (int off = 32; off > 0; off >>= 1) mx = fmaxf(mx, __shfl_down(mx, off, 64));
    if (lane == 0) scr[wid] = mx;
    __syncthreads();
    if (tid == 0) scr[0] = fmaxf(fmaxf(scr[0], scr[1]), fmaxf(scr[2], scr[3]));
    __syncthreads();
    float m = scr[0];
    __syncthreads();

    float s = 0.0f;
    for (int i = tid; i < HW_; i += 256) {
        float e = __expf(row[i] - m);
        row[i] = e;
        s += e;
    }
    #pragma unroll
    for (int off = 32; off > 0; off >>= 1) s += __shfl_down(s, off, 64);
    if (lane == 0) scr[wid] = s;
    __syncthreads();
    if (tid == 0) scr[0] = scr[0] + scr[1] + scr[2] + scr[3];
    __syncthreads();
    float inv = 1.0f / scr[0];

    for (int i = tid; i < HW_; i += 256) tr[i] = row[i] * inv;
}

// ---------------------------------------------------------------------------
// Kernel 5: xz = att * (Wz @ ts) per group, in place over tbuf (f32).
// Accumulates per-(b,gi) sum / sumsq into stats.
// ---------------------------------------------------------------------------
__global__ __launch_bounds__(256) void k_xz(
    float* __restrict__ tbuf, const float* __restrict__ Wz,
    const float* __restrict__ att, float* __restrict__ stats)
{
    __shared__ float ts[32][256];
    __shared__ float wz[32][32];
    __shared__ float scr[8];
    int pt  = blockIdx.x;   // 0..15
    int gi  = blockIdx.y;   // 0..7
    int b   = blockIdx.z;   // 0..15
    int tid = threadIdx.x;
    int pix0 = pt * 256;

    float* base = tbuf + ((size_t)b * 256 + gi * 32) * HW_;
    #pragma unroll 4
    for (int i = 0; i < 32; ++i) ts[i][tid] = base[(size_t)i * HW_ + pix0 + tid];
    const float* wzg = Wz + gi * 32 * 32;
    #pragma unroll
    for (int i = 0; i < 4; ++i) {
        int idx = tid + i * 256;
        wz[idx >> 5][idx & 31] = wzg[idx];
    }
    __syncthreads();

    float a = att[b * 8 + gi];
    float v[32];
    #pragma unroll
    for (int i = 0; i < 32; ++i) v[i] = ts[i][tid];

    float s1 = 0.0f, s2 = 0.0f;
    for (int o = 0; o < 32; ++o) {
        float acc = 0.0f;
        #pragma unroll
        for (int i = 0; i < 32; ++i) acc = fmaf(wz[o][i], v[i], acc);
        acc *= a;
        base[(size_t)o * HW_ + pix0 + tid] = acc;
        s1 += acc;
        s2 = fmaf(acc, acc, s2);
    }

    #pragma unroll
    for (int off = 32; off > 0; off >>= 1) {
        s1 += __shfl_down(s1, off, 64);
        s2 += __shfl_down(s2, off, 64);
    }
    int lane = tid & 63, wid = tid >> 6;
    if (lane == 0) { scr[wid] = s1; scr[4 + wid] = s2; }
    __syncthreads();
    if (tid == 0) {
        atomicAdd(&stats[(b * 8 + gi) * 2 + 0], scr[0] + scr[1] + scr[2] + scr[3]);
        atomicAdd(&stats[(b * 8 + gi) * 2 + 1], scr[4] + scr[5] + scr[6] + scr[7]);
    }
}

// ---------------------------------------------------------------------------
// Kernel 6: GroupNorm finalize + affine + residual
// ---------------------------------------------------------------------------
__global__ __launch_bounds__(256) void k_finalize(
    const float* __restrict__ xzbuf, const float* __restrict__ x,
    const float* __restrict__ stats, const float* __restrict__ gamma,
    const float* __restrict__ beta, float* __restrict__ out)
{
    size_t idx = (size_t)blockIdx.x * 256 + threadIdx.x;
    int c  = (int)((idx >> 12) & 255);
    int bg = (int)(idx >> 17);
    float s1 = stats[bg * 2], s2 = stats[bg * 2 + 1];
    const float invN = 1.0f / 131072.0f;
    float mu  = s1 * invN;
    float var = s2 * invN - mu * mu;
    float rs  = rsqrtf(var + EPSV);
    out[idx] = (xzbuf[idx] - mu) * rs * gamma[c] + beta[c] + x[idx];
}

// ---------------------------------------------------------------------------
extern "C" void kernel_launch(void* const* d_in, const int* in_sizes, int n_in,
                              void* d_out, int out_size, void* d_ws, size_t ws_size,
                              hipStream_t stream)
{
    const float* x     = (const float*)d_in[0];
    const float* mask  = (const float*)d_in[1];
    const float* Wt    = (const float*)d_in[2];
    const float* Wtm   = (const float*)d_in[3];
    const float* Wp    = (const float*)d_in[4];
    const float* Wg    = (const float*)d_in[5];
    const float* Wz    = (const float*)d_in[6];
    const float* gamma = (const float*)d_in[7];
    const float* beta  = (const float*)d_in[8];
    float* out = (float*)d_out;

    // workspace layout (bytes), total ~101.5 MB (< proven 128.3 MB):
    //   tbuf  (f32, full batch): 67,108,864   (t -> ts -> xz in place)
    //   xThi / xTlo (bf16, quarter batch): 8,388,608 each
    //   pbufq / gbufq (f32, quarter batch): 8,388,608 each
    //   pAhi/pAlo: 262,144 each ; tmod (f32): 262,144 ; att/stats: 1,536
    char* ws = (char*)d_ws;
    float* tbuf  = (float*)(ws);
    u16*   xThi  = (u16*)(ws + 67108864);
    u16*   xTlo  = (u16*)(ws + 75497472);
    float* pbufq = (float*)(ws + 83886080);
    float* gbufq = (float*)(ws + 92274688);
    u16*   pAhi  = (u16*)(ws + 100663296);
    u16*   pAlo  = (u16*)(ws + 100925440);
    float* tmod  = (float*)(ws + 101187584);
    float* att   = (float*)(ws + 101449728);
    float* stats = att + 128;

    k_packA    <<<64, 256, 0, stream>>>(Wt, Wp, Wg, pAhi, pAlo);
    k_tmod_zero<<<256, 256, 0, stream>>>(mask, Wtm, tmod, att, stats);
    for (int b0 = 0; b0 < 16; b0 += 4) {
        k_transpose<<<dim3(32, 8, 4), 256, 0, stream>>>(x, xThi, xTlo, b0);
        k_mm<<<dim3(32, 2, 4), 256, 0, stream>>>(xThi, xTlo, pAhi, pAlo, tmod,
                                                 tbuf, pbufq, gbufq, b0, 0);
        k_mm<<<dim3(32, 2, 4), 256, 0, stream>>>(xThi, xTlo, pAhi, pAlo, tmod,
                                                 tbuf, pbufq, gbufq, b0, 1);
        k_att<<<dim3(32, 4, 4), 256, 0, stream>>>(pbufq, gbufq, att, b0);
    }
    k_softmax  <<<4096, 256, 0, stream>>>(tbuf);
    k_xz       <<<dim3(16, 8, 16), 256, 0, stream>>>(tbuf, Wz, att, stats);
    k_finalize <<<65536, 256, 0, stream>>>(tbuf, x, stats, gamma, beta, out);
}

// Round 7
// 311.459 us; speedup vs baseline: 2.2964x; 1.0920x over previous
//
#include <hip/hip_runtime.h>
#include <math.h>

#define B_      16
#define CIN     256
#define HW_     4096          // 64x64
#define PLANES  256
#define G_      8
#define EPSV    1e-5f

typedef unsigned short u16;
typedef __attribute__((ext_vector_type(8))) short short8;   // 8 bf16 (4 VGPRs)
typedef __attribute__((ext_vector_type(4))) float f32x4;    // MFMA acc

__device__ inline u16 f2bf(float f) {
    union { float f; unsigned u; } v; v.f = f;
    unsigned u = v.u;
    return (u16)((u + 0x7fffu + ((u >> 16) & 1u)) >> 16);   // RNE
}
__device__ inline float bf2f(u16 h) {
    union { unsigned u; float f; } v; v.u = ((unsigned)h) << 16;
    return v.f;
}

// ---------------------------------------------------------------------------
// Kernel 0a: pack Wt|Wp|Wg (512x256 f32) into MFMA A-fragment order, split
// into bf16 hi + lo (w = hi + lo, exact to ~2^-16 rel).
// slot (rt 0..3, kt 0..7, mb 0..7, lane 0..63, j 0..7):
//   row = rt*128 + mb*16 + (lane&15); k = kt*32 + (lane>>4)*8 + j
// ---------------------------------------------------------------------------
__global__ __launch_bounds__(256) void k_packA(
    const float* __restrict__ Wt, const float* __restrict__ Wp,
    const float* __restrict__ Wg,
    u16* __restrict__ pAhi, u16* __restrict__ pAlo)
{
    int t = blockIdx.x * 256 + threadIdx.x;      // 0..16383
    int lane = t & 63;
    int mb   = (t >> 6) & 7;
    int kt   = (t >> 9) & 7;
    int rt   = (t >> 12) & 3;
    int row = rt * 128 + mb * 16 + (lane & 15);
    int k0  = kt * 32 + (lane >> 4) * 8;
    const float* src;
    if      (row < 256) src = Wt + (size_t)row * 256;
    else if (row < 384) src = Wp + (size_t)(row - 256) * 256;
    else                src = Wg + (size_t)(row - 384) * 256;
    u16 hv[8], lv[8];
    #pragma unroll
    for (int j = 0; j < 8; ++j) {
        float w = src[k0 + j];
        u16 h = f2bf(w);
        hv[j] = h;
        lv[j] = f2bf(w - bf2f(h));
    }
    *(short8*)(pAhi + (size_t)t * 8) = *(short8*)hv;
    *(short8*)(pAlo + (size_t)t * 8) = *(short8*)lv;
}

// ---------------------------------------------------------------------------
// Kernel 0b: transpose x[b0+bz][256][4096] f32 -> xThi/xTlo[bz][4096][256]
// bf16 hi/lo split.  Quarter-batch (bz 0..3) per pass.
// ---------------------------------------------------------------------------
__global__ __launch_bounds__(256) void k_transpose(
    const float* __restrict__ x, u16* __restrict__ xThi,
    u16* __restrict__ xTlo, int b0)
{
    __shared__ float tile[32][129];
    int tid = threadIdx.x;
    int px0 = blockIdx.x * 128;
    int c0  = blockIdx.y * 32;
    int bz  = blockIdx.z;
    int bg  = b0 + bz;

    #pragma unroll
    for (int it = 0; it < 16; ++it) {
        int flat = it * 256 + tid;
        int c_l = flat >> 7, p_l = flat & 127;
        tile[c_l][p_l] = x[((size_t)bg * 256 + c0 + c_l) * 4096 + px0 + p_l];
    }
    __syncthreads();
    #pragma unroll
    for (int it = 0; it < 8; ++it) {
        int flat = it * 256 + tid;          // 0..2047
        int p_l = flat >> 4;
        int c_l = (flat & 15) * 2;
        float v0 = tile[c_l][p_l], v1 = tile[c_l + 1][p_l];
        u16 h0 = f2bf(v0), h1 = f2bf(v1);
        u16 l0 = f2bf(v0 - bf2f(h0)), l1 = f2bf(v1 - bf2f(h1));
        size_t o = ((size_t)bz * 4096 + px0 + p_l) * 256 + c0 + c_l;
        u16 ho[2] = { h0, h1 };
        u16 lo[2] = { l0, l1 };
        *(unsigned*)(xThi + o) = *(unsigned*)ho;
        *(unsigned*)(xTlo + o) = *(unsigned*)lo;
    }
}

// ---------------------------------------------------------------------------
// Kernel 1: tmod + zero att/stats
// ---------------------------------------------------------------------------
__global__ __launch_bounds__(256) void k_tmod_zero(
    const float* __restrict__ mask, const float* __restrict__ Wtm,
    float* __restrict__ tmod, float* __restrict__ att, float* __restrict__ stats)
{
    int idx = blockIdx.x * 256 + threadIdx.x;
    float w0 = Wtm[0], w1 = Wtm[1];
    if (idx < B_ * HW_) {
        int b = idx >> 12, pix = idx & 4095;
        const float* mb = mask + (size_t)b * 2 * HW_;
        tmod[idx] = 1.0f + w0 * mb[pix] + w1 * mb[HW_ + pix];
    }
    if (blockIdx.x == 0) {
        if (threadIdx.x < 128) att[threadIdx.x] = 0.0f;
        stats[threadIdx.x] = 0.0f;
    }
}

// ---------------------------------------------------------------------------
// Kernel 2: MFMA GEMM, quarter batch (4 images), two modes:
//   mode 0 (t rows 0..255):  1 pass  Whi*xhi          -> f32 tbuf (* tmod)
//   mode 1 (p/g rows 256..511): 3 passes Whi*xhi + Wlo*xhi + Whi*xlo
//                             (f32-exact)             -> f32 pbufq/gbufq
// Block: 128 rows x 128 px, 4 waves (2x2).  64 KB LDS B-panel, XOR-swizzled.
// ---------------------------------------------------------------------------
#define STAGE(SRC)                                                            \
    _Pragma("unroll")                                                         \
    for (int it = 0; it < 16; ++it) {                                         \
        int cidx = it * 256 + tid;                                            \
        int px   = cidx >> 5;                                                 \
        int boff = (cidx & 31) << 4;                                          \
        short8 v = *(const short8*)((SRC) + (size_t)px * 512 + boff);         \
        *(short8*)(Blds + px * 512 + (boff ^ ((px & 7) << 4))) = v;           \
    }

#define MFMA_PASS(ASRC)                                                       \
    _Pragma("unroll")                                                         \
    for (int kt = 0; kt < 8; ++kt) {                                          \
        short8 a[4], bb[4];                                                   \
        _Pragma("unroll")                                                     \
        for (int m = 0; m < 4; ++m)                                           \
            a[m] = *(const short8*)((ASRC) +                                  \
                ((((size_t)(rt * 8 + kt) * 8) + wm * 4 + m) * 64 + lane) * 8);\
        int off = ((kt * 64) + ((lane >> 4) << 4)) ^ ((lane & 7) << 4);       \
        _Pragma("unroll")                                                     \
        for (int n = 0; n < 4; ++n) {                                         \
            int px = wn * 64 + n * 16 + (lane & 15);                          \
            bb[n] = *(const short8*)(Blds + px * 512 + off);                  \
        }                                                                     \
        _Pragma("unroll")                                                     \
        for (int m = 0; m < 4; ++m)                                           \
            _Pragma("unroll")                                                 \
            for (int n = 0; n < 4; ++n)                                       \
                acc[m][n] = __builtin_amdgcn_mfma_f32_16x16x32_bf16(          \
                    a[m], bb[n], acc[m][n], 0, 0, 0);                         \
    }

__global__ __launch_bounds__(256) void k_mm(
    const u16* __restrict__ xThi, const u16* __restrict__ xTlo,
    const u16* __restrict__ pAhi, const u16* __restrict__ pAlo,
    const float* __restrict__ tmod,
    float* __restrict__ tbuf, float* __restrict__ pbufq, float* __restrict__ gbufq,
    int b0, int mode)
{
    __shared__ short8 BldsV[4096];           // 64 KB
    char* Blds = (char*)BldsV;
    int tid = threadIdx.x, lane = tid & 63, wid = tid >> 6;
    int wm = wid >> 1, wn = wid & 1;
    int pix0 = blockIdx.x * 128;
    int by   = blockIdx.y;                   // 0..1
    int rt   = (mode ? 2 : 0) + by;          // global 128-row tile index
    int bz = blockIdx.z, bg = b0 + bz;

    const char* srcHi = (const char*)(xThi + ((size_t)bz * 4096 + pix0) * 256);
    const char* srcLo = (const char*)(xTlo + ((size_t)bz * 4096 + pix0) * 256);

    f32x4 acc[4][4];
    #pragma unroll
    for (int m = 0; m < 4; ++m)
        #pragma unroll
        for (int n = 0; n < 4; ++n) acc[m][n] = (f32x4)0.0f;

    STAGE(srcHi);
    __syncthreads();
    MFMA_PASS(pAhi);
    if (mode) {
        MFMA_PASS(pAlo);
        __syncthreads();     // all waves done reading hi panel
        STAGE(srcLo);
        __syncthreads();
        MFMA_PASS(pAhi);
    }

    // ---- epilogue: D row = (lane>>4)*4 + r (M), col = lane&15 (N) ----
    int colb = pix0 + wn * 64;
    if (mode == 0) {
        int rowb = by * 128 + wm * 64;       // 0..255 within t
        float tm[4];
        #pragma unroll
        for (int n = 0; n < 4; ++n) tm[n] = tmod[bg * 4096 + colb + n * 16 + (lane & 15)];
        #pragma unroll
        for (int m = 0; m < 4; ++m)
            #pragma unroll
            for (int n = 0; n < 4; ++n)
                #pragma unroll
                for (int r = 0; r < 4; ++r) {
                    int row = rowb + m * 16 + (lane >> 4) * 4 + r;
                    int col = colb + n * 16 + (lane & 15);
                    tbuf[((size_t)bg * 256 + row) * 4096 + col] = acc[m][n][r] * tm[n];
                }
    } else {
        float* dst = (by == 0) ? pbufq : gbufq;   // by0: p rows, by1: g rows
        int rowb = wm * 64;                  // 0..127 within p or g
        #pragma unroll
        for (int m = 0; m < 4; ++m)
            #pragma unroll
            for (int n = 0; n < 4; ++n)
                #pragma unroll
                for (int r = 0; r < 4; ++r) {
                    int row = rowb + m * 16 + (lane >> 4) * 4 + r;
                    int col = colb + n * 16 + (lane & 15);
                    dst[((size_t)bz * 128 + row) * 4096 + col] = acc[m][n][r];
                }
    }
}

// ---------------------------------------------------------------------------
// Kernel 3: attention dot (f32), quarter batch.  Block per (c, gi, bz).
// ---------------------------------------------------------------------------
__global__ __launch_bounds__(256) void k_att(
    const float* __restrict__ pbufq, const float* __restrict__ gbufq,
    float* __restrict__ att, int b0)
{
    __shared__ float plds[HW_];
    __shared__ float glds[HW_];
    __shared__ float scr[8];
    int c  = blockIdx.x;   // 0..31
    int gi = blockIdx.y;   // 0..3
    int bz = blockIdx.z;   // 0..3
    int tid = threadIdx.x;

    const float* pp = pbufq + ((size_t)bz * 128 + gi * 32 + c) * HW_;
    const float* gg = gbufq + ((size_t)bz * 128 + gi * 32 + c) * HW_;

    float racc = 0.0f;
    #pragma unroll
    for (int it = 0; it < 4; ++it) {
        int i = it * 1024 + tid * 4;
        float4 pv = *(const float4*)(pp + i);
        float4 gv = *(const float4*)(gg + i);
        *(float4*)(&plds[i]) = pv;
        *(float4*)(&glds[i]) = gv;
        racc += pv.x * gv.x + pv.y * gv.y + pv.z * gv.z + pv.w * gv.w;
    }
    __syncthreads();

    float pacc = 0.0f;
    #pragma unroll 4
    for (int i = tid; i < HW_; i += 256) {
        int h = i >> 6, w = i & 63;
        int h0 = max(h - 1, 0), h1 = min(h + 1, 63);
        int w0 = max(w - 1, 0), w1 = min(w + 1, 63);
        float mp = -3.0e38f, mg = -3.0e38f;
        for (int hh = h0; hh <= h1; ++hh)
            for (int ww = w0; ww <= w1; ++ww) {
                mp = fmaxf(mp, plds[hh * 64 + ww]);
                mg = fmaxf(mg, glds[hh * 64 + ww]);
            }
        pacc += mp * mg;
    }

    #pragma unroll
    for (int off = 32; off > 0; off >>= 1) {
        racc += __shfl_down(racc, off, 64);
        pacc += __shfl_down(pacc, off, 64);
    }
    int lane = tid & 63, wid = tid >> 6;
    if (lane == 0) { scr[wid] = racc; scr[4 + wid] = pacc; }
    __syncthreads();
    if (tid == 0) {
        int bg = b0 + bz;
        atomicAdd(&att[bg * 8 + gi],     scr[0] + scr[1] + scr[2] + scr[3]);
        atomicAdd(&att[bg * 8 + gi + 4], scr[4] + scr[5] + scr[6] + scr[7]);
    }
}

// ---------------------------------------------------------------------------
// Kernel 4: per-row softmax stats only.  Block per (b,c) row; registers only.
//   rowstat[r] = (rowmax, 1/sum(exp(v - rowmax)))
// ---------------------------------------------------------------------------
__global__ __launch_bounds__(256) void k_smax(
    const float* __restrict__ tbuf, float2* __restrict__ rowstat)
{
    __shared__ float scr[8];
    int r = blockIdx.x;
    const float* tr = tbuf + (size_t)r * HW_;
    int tid = threadIdx.x;
    int lane = tid & 63, wid = tid >> 6;

    float4 v[4];
    float mx = -3.0e38f;
    #pragma unroll
    for (int it = 0; it < 4; ++it) {
        v[it] = *(const float4*)(tr + it * 1024 + tid * 4);
        mx = fmaxf(mx, fmaxf(fmaxf(v[it].x, v[it].y), fmaxf(v[it].z, v[it].w)));
    }
    #pragma unroll
    for (int off = 32; off > 0; off >>= 1) mx = fmaxf(mx, __shfl_down(mx, off, 64));
    if (lane == 0) scr[wid] = mx;
    __syncthreads();
    if (tid == 0) scr[0] = fmaxf(fmaxf(scr[0], scr[1]), fmaxf(scr[2], scr[3]));
    __syncthreads();
    float m = scr[0];
    __syncthreads();

    float s = 0.0f;
    #pragma unroll
    for (int it = 0; it < 4; ++it) {
        s += __expf(v[it].x - m) + __expf(v[it].y - m)
           + __expf(v[it].z - m) + __expf(v[it].w - m);
    }
    #pragma unroll
    for (int off = 32; off > 0; off >>= 1) s += __shfl_down(s, off, 64);
    if (lane == 0) scr[4 + wid] = s;
    __syncthreads();
    if (tid == 0) {
        float S = scr[4] + scr[5] + scr[6] + scr[7];
        rowstat[r] = make_float2(m, 1.0f / S);
    }
}

// ---------------------------------------------------------------------------
// Kernel 5: fused softmax-apply + xz mix + GN stats, in place over tbuf.
//   xz[b, gi*32+o, px] = att[b,gi] * sum_i Wz[gi,o,i] * exp(t[..i..]-m_i)*inv_i
// Block per (pt 512px, gi, b); 2 px per thread; wz in 4 KB LDS (broadcast
// float4 reads); ts kept in registers (no LDS round trip).
// ---------------------------------------------------------------------------
__global__ __launch_bounds__(256) void k_xz2(
    float* __restrict__ tbuf, const float* __restrict__ Wz,
    const float2* __restrict__ rowstat, const float* __restrict__ att,
    float* __restrict__ stats)
{
    __shared__ float wz[32][32];
    __shared__ float2 rs[32];
    __shared__ float scr[8];
    int pt  = blockIdx.x;   // 0..7  (512-pixel tile)
    int gi  = blockIdx.y;   // 0..7
    int b   = blockIdx.z;   // 0..15
    int tid = threadIdx.x;
    int px  = pt * 512 + tid * 2;

    const float* wzg = Wz + gi * 1024;
    #pragma unroll
    for (int i = 0; i < 4; ++i) {
        int idx = tid + i * 256;
        wz[idx >> 5][idx & 31] = wzg[idx];
    }
    if (tid < 32) rs[tid] = rowstat[b * 256 + gi * 32 + tid];
    __syncthreads();

    float* base = tbuf + ((size_t)b * 256 + gi * 32) * HW_;
    float2 v[32];
    #pragma unroll
    for (int i = 0; i < 32; ++i) {
        float2 r2 = *(const float2*)(base + (size_t)i * HW_ + px);
        float m = rs[i].x, inv = rs[i].y;
        v[i].x = __expf(r2.x - m) * inv;
        v[i].y = __expf(r2.y - m) * inv;
    }

    float a = att[b * 8 + gi];
    float s1 = 0.0f, s2 = 0.0f;
    #pragma unroll
    for (int o = 0; o < 32; ++o) {
        const float4* wzo = (const float4*)(&wz[o][0]);
        float ax = 0.0f, ay = 0.0f;
        #pragma unroll
        for (int j = 0; j < 8; ++j) {
            float4 w = wzo[j];
            ax = fmaf(w.x, v[4*j+0].x, ax); ay = fmaf(w.x, v[4*j+0].y, ay);
            ax = fmaf(w.y, v[4*j+1].x, ax); ay = fmaf(w.y, v[4*j+1].y, ay);
            ax = fmaf(w.z, v[4*j+2].x, ax); ay = fmaf(w.z, v[4*j+2].y, ay);
            ax = fmaf(w.w, v[4*j+3].x, ax); ay = fmaf(w.w, v[4*j+3].y, ay);
        }
        ax *= a; ay *= a;
        *(float2*)(base + (size_t)o * HW_ + px) = make_float2(ax, ay);
        s1 += ax + ay;
        s2 = fmaf(ax, ax, fmaf(ay, ay, s2));
    }

    #pragma unroll
    for (int off = 32; off > 0; off >>= 1) {
        s1 += __shfl_down(s1, off, 64);
        s2 += __shfl_down(s2, off, 64);
    }
    int lane = tid & 63, wid = tid >> 6;
    if (lane == 0) { scr[wid] = s1; scr[4 + wid] = s2; }
    __syncthreads();
    if (tid == 0) {
        atomicAdd(&stats[(b * 8 + gi) * 2 + 0], scr[0] + scr[1] + scr[2] + scr[3]);
        atomicAdd(&stats[(b * 8 + gi) * 2 + 1], scr[4] + scr[5] + scr[6] + scr[7]);
    }
}

// ---------------------------------------------------------------------------
// Kernel 6: GroupNorm finalize + affine + residual
// ---------------------------------------------------------------------------
__global__ __launch_bounds__(256) void k_finalize(
    const float* __restrict__ xzbuf, const float* __restrict__ x,
    const float* __restrict__ stats, const float* __restrict__ gamma,
    const float* __restrict__ beta, float* __restrict__ out)
{
    size_t idx = (size_t)blockIdx.x * 256 + threadIdx.x;
    int c  = (int)((idx >> 12) & 255);
    int bg = (int)(idx >> 17);
    float s1 = stats[bg * 2], s2 = stats[bg * 2 + 1];
    const float invN = 1.0f / 131072.0f;
    float mu  = s1 * invN;
    float var = s2 * invN - mu * mu;
    float rs  = rsqrtf(var + EPSV);
    out[idx] = (xzbuf[idx] - mu) * rs * gamma[c] + beta[c] + x[idx];
}

// ---------------------------------------------------------------------------
extern "C" void kernel_launch(void* const* d_in, const int* in_sizes, int n_in,
                              void* d_out, int out_size, void* d_ws, size_t ws_size,
                              hipStream_t stream)
{
    const float* x     = (const float*)d_in[0];
    const float* mask  = (const float*)d_in[1];
    const float* Wt    = (const float*)d_in[2];
    const float* Wtm   = (const float*)d_in[3];
    const float* Wp    = (const float*)d_in[4];
    const float* Wg    = (const float*)d_in[5];
    const float* Wz    = (const float*)d_in[6];
    const float* gamma = (const float*)d_in[7];
    const float* beta  = (const float*)d_in[8];
    float* out = (float*)d_out;

    // workspace layout (bytes), total ~101.5 MB (< proven 128.3 MB):
    //   tbuf  (f32, full batch): 67,108,864   (t -> xz in place)
    //   xThi / xTlo (bf16, quarter batch): 8,388,608 each
    //   pbufq / gbufq (f32, quarter batch): 8,388,608 each
    //   pAhi/pAlo: 262,144 each ; tmod (f32): 262,144
    //   att/stats: 1,536 ; rowstat (float2[4096]): 32,768
    char* ws = (char*)d_ws;
    float* tbuf  = (float*)(ws);
    u16*   xThi  = (u16*)(ws + 67108864);
    u16*   xTlo  = (u16*)(ws + 75497472);
    float* pbufq = (float*)(ws + 83886080);
    float* gbufq = (float*)(ws + 92274688);
    u16*   pAhi  = (u16*)(ws + 100663296);
    u16*   pAlo  = (u16*)(ws + 100925440);
    float* tmod  = (float*)(ws + 101187584);
    float* att   = (float*)(ws + 101449728);
    float* stats = att + 128;
    float2* rowstat = (float2*)(ws + 101451776);

    k_packA    <<<64, 256, 0, stream>>>(Wt, Wp, Wg, pAhi, pAlo);
    k_tmod_zero<<<256, 256, 0, stream>>>(mask, Wtm, tmod, att, stats);
    for (int b0 = 0; b0 < 16; b0 += 4) {
        k_transpose<<<dim3(32, 8, 4), 256, 0, stream>>>(x, xThi, xTlo, b0);
        k_mm<<<dim3(32, 2, 4), 256, 0, stream>>>(xThi, xTlo, pAhi, pAlo, tmod,
                                                 tbuf, pbufq, gbufq, b0, 0);
        k_mm<<<dim3(32, 2, 4), 256, 0, stream>>>(xThi, xTlo, pAhi, pAlo, tmod,
                                                 tbuf, pbufq, gbufq, b0, 1);
        k_att<<<dim3(32, 4, 4), 256, 0, stream>>>(pbufq, gbufq, att, b0);
    }
    k_smax     <<<4096, 256, 0, stream>>>(tbuf, rowstat);
    k_xz2      <<<dim3(8, 8, 16), 256, 0, stream>>>(tbuf, Wz, rowstat, att, stats);
    k_finalize <<<65536, 256, 0, stream>>>(tbuf, x, stats, gamma, beta, out);
}

// Round 8
// 274.835 us; speedup vs baseline: 2.6024x; 1.1333x over previous
//
#include <hip/hip_runtime.h>
#include <math.h>

#define B_      16
#define CIN     256
#define HW_     4096          // 64x64
#define PLANES  256
#define G_      8
#define EPSV    1e-5f

typedef unsigned short u16;
typedef __attribute__((ext_vector_type(8))) short short8;   // 8 bf16 (4 VGPRs)
typedef __attribute__((ext_vector_type(4))) float f32x4;    // MFMA acc

__device__ inline u16 f2bf(float f) {
    union { float f; unsigned u; } v; v.f = f;
    unsigned u = v.u;
    return (u16)((u + 0x7fffu + ((u >> 16) & 1u)) >> 16);   // RNE
}
__device__ inline float bf2f(u16 h) {
    union { unsigned u; float f; } v; v.u = ((unsigned)h) << 16;
    return v.f;
}

// ---------------------------------------------------------------------------
// Kernel 0a: pack Wt|Wp|Wg (512x256 f32) into MFMA A-fragment order, split
// into bf16 hi + lo (w = hi + lo, exact to ~2^-16 rel).
// slot (rt 0..3, kt 0..7, mb 0..7, lane 0..63, j 0..7):
//   row = rt*128 + mb*16 + (lane&15); k = kt*32 + (lane>>4)*8 + j
// ---------------------------------------------------------------------------
__global__ __launch_bounds__(256) void k_packA(
    const float* __restrict__ Wt, const float* __restrict__ Wp,
    const float* __restrict__ Wg,
    u16* __restrict__ pAhi, u16* __restrict__ pAlo)
{
    int t = blockIdx.x * 256 + threadIdx.x;      // 0..16383
    int lane = t & 63;
    int mb   = (t >> 6) & 7;
    int kt   = (t >> 9) & 7;
    int rt   = (t >> 12) & 3;
    int row = rt * 128 + mb * 16 + (lane & 15);
    int k0  = kt * 32 + (lane >> 4) * 8;
    const float* src;
    if      (row < 256) src = Wt + (size_t)row * 256;
    else if (row < 384) src = Wp + (size_t)(row - 256) * 256;
    else                src = Wg + (size_t)(row - 384) * 256;
    u16 hv[8], lv[8];
    #pragma unroll
    for (int j = 0; j < 8; ++j) {
        float w = src[k0 + j];
        u16 h = f2bf(w);
        hv[j] = h;
        lv[j] = f2bf(w - bf2f(h));
    }
    *(short8*)(pAhi + (size_t)t * 8) = *(short8*)hv;
    *(short8*)(pAlo + (size_t)t * 8) = *(short8*)lv;
}

// ---------------------------------------------------------------------------
// Kernel 0b: transpose x[b][256][4096] f32 -> xThi/xTlo[b][4096][256]
// bf16 hi/lo split.  FULL batch, one launch (4096 blocks).
// ---------------------------------------------------------------------------
__global__ __launch_bounds__(256) void k_transpose(
    const float* __restrict__ x, u16* __restrict__ xThi,
    u16* __restrict__ xTlo)
{
    __shared__ float tile[32][129];
    int tid = threadIdx.x;
    int px0 = blockIdx.x * 128;
    int c0  = blockIdx.y * 32;
    int bg  = blockIdx.z;

    #pragma unroll
    for (int it = 0; it < 16; ++it) {
        int flat = it * 256 + tid;
        int c_l = flat >> 7, p_l = flat & 127;
        tile[c_l][p_l] = x[((size_t)bg * 256 + c0 + c_l) * 4096 + px0 + p_l];
    }
    __syncthreads();
    #pragma unroll
    for (int it = 0; it < 8; ++it) {
        int flat = it * 256 + tid;          // 0..2047
        int p_l = flat >> 4;
        int c_l = (flat & 15) * 2;
        float v0 = tile[c_l][p_l], v1 = tile[c_l + 1][p_l];
        u16 h0 = f2bf(v0), h1 = f2bf(v1);
        u16 l0 = f2bf(v0 - bf2f(h0)), l1 = f2bf(v1 - bf2f(h1));
        size_t o = ((size_t)bg * 4096 + px0 + p_l) * 256 + c0 + c_l;
        u16 ho[2] = { h0, h1 };
        u16 lo[2] = { l0, l1 };
        *(unsigned*)(xThi + o) = *(unsigned*)ho;
        *(unsigned*)(xTlo + o) = *(unsigned*)lo;
    }
}

// ---------------------------------------------------------------------------
// Kernel 1: tmod + zero att/stats
// ---------------------------------------------------------------------------
__global__ __launch_bounds__(256) void k_tmod_zero(
    const float* __restrict__ mask, const float* __restrict__ Wtm,
    float* __restrict__ tmod, float* __restrict__ att, float* __restrict__ stats)
{
    int idx = blockIdx.x * 256 + threadIdx.x;
    float w0 = Wtm[0], w1 = Wtm[1];
    if (idx < B_ * HW_) {
        int b = idx >> 12, pix = idx & 4095;
        const float* mb = mask + (size_t)b * 2 * HW_;
        tmod[idx] = 1.0f + w0 * mb[pix] + w1 * mb[HW_ + pix];
    }
    if (blockIdx.x == 0) {
        if (threadIdx.x < 128) att[threadIdx.x] = 0.0f;
        stats[threadIdx.x] = 0.0f;
    }
}

// ---------------------------------------------------------------------------
// Shared GEMM building blocks.  Block: 128 rows x 128 px, 4 waves (2x2).
// 64 KB LDS B-panel, XOR-swizzled.
// ---------------------------------------------------------------------------
#define STAGE(SRC)                                                            \
    _Pragma("unroll")                                                         \
    for (int it = 0; it < 16; ++it) {                                         \
        int cidx = it * 256 + tid;                                            \
        int px   = cidx >> 5;                                                 \
        int boff = (cidx & 31) << 4;                                          \
        short8 v = *(const short8*)((SRC) + (size_t)px * 512 + boff);         \
        *(short8*)(Blds + px * 512 + (boff ^ ((px & 7) << 4))) = v;           \
    }

#define MFMA_PASS(ASRC)                                                       \
    _Pragma("unroll")                                                         \
    for (int kt = 0; kt < 8; ++kt) {                                          \
        short8 a[4], bb[4];                                                   \
        _Pragma("unroll")                                                     \
        for (int m = 0; m < 4; ++m)                                           \
            a[m] = *(const short8*)((ASRC) +                                  \
                ((((size_t)(rt * 8 + kt) * 8) + wm * 4 + m) * 64 + lane) * 8);\
        int off = ((kt * 64) + ((lane >> 4) << 4)) ^ ((lane & 7) << 4);       \
        _Pragma("unroll")                                                     \
        for (int n = 0; n < 4; ++n) {                                         \
            int px = wn * 64 + n * 16 + (lane & 15);                          \
            bb[n] = *(const short8*)(Blds + px * 512 + off);                  \
        }                                                                     \
        _Pragma("unroll")                                                     \
        for (int m = 0; m < 4; ++m)                                           \
            _Pragma("unroll")                                                 \
            for (int n = 0; n < 4; ++n)                                       \
                acc[m][n] = __builtin_amdgcn_mfma_f32_16x16x32_bf16(          \
                    a[m], bb[n], acc[m][n], 0, 0, 0);                         \
    }

// ---------------------------------------------------------------------------
// Kernel 2a: t-GEMM, FULL batch, 1 bf16 pass -> bf16 tbuf (* tmod).
// Grid (32 px-tiles, 2 row-tiles, 16 b) = 1024 blocks.
// ---------------------------------------------------------------------------
__global__ __launch_bounds__(256) void k_mm0(
    const u16* __restrict__ xThi, const u16* __restrict__ pAhi,
    const float* __restrict__ tmod, u16* __restrict__ tbuf)
{
    __shared__ short8 BldsV[4096];           // 64 KB
    char* Blds = (char*)BldsV;
    int tid = threadIdx.x, lane = tid & 63, wid = tid >> 6;
    int wm = wid >> 1, wn = wid & 1;
    int pix0 = blockIdx.x * 128;
    int rt   = blockIdx.y;                   // 0..1 (t rows)
    int bg   = blockIdx.z;

    const char* srcHi = (const char*)(xThi + ((size_t)bg * 4096 + pix0) * 256);

    f32x4 acc[4][4];
    #pragma unroll
    for (int m = 0; m < 4; ++m)
        #pragma unroll
        for (int n = 0; n < 4; ++n) acc[m][n] = (f32x4)0.0f;

    STAGE(srcHi);
    __syncthreads();
    MFMA_PASS(pAhi);

    int colb = pix0 + wn * 64;
    int rowb = rt * 128 + wm * 64;
    float tm[4];
    #pragma unroll
    for (int n = 0; n < 4; ++n) tm[n] = tmod[bg * 4096 + colb + n * 16 + (lane & 15)];
    #pragma unroll
    for (int m = 0; m < 4; ++m)
        #pragma unroll
        for (int n = 0; n < 4; ++n)
            #pragma unroll
            for (int r = 0; r < 4; ++r) {
                int row = rowb + m * 16 + (lane >> 4) * 4 + r;
                int col = colb + n * 16 + (lane & 15);
                tbuf[((size_t)bg * 256 + row) * 4096 + col] = f2bf(acc[m][n][r] * tm[n]);
            }
}

// ---------------------------------------------------------------------------
// Kernel 2b: p/g-GEMM, quarter batch, 3 passes (f32-exact) -> f32 pbufq/gbufq.
// Grid (32 px-tiles, 2 {p,g}, 4 bz) = 256 blocks.
// ---------------------------------------------------------------------------
__global__ __launch_bounds__(256) void k_mm1(
    const u16* __restrict__ xThi, const u16* __restrict__ xTlo,
    const u16* __restrict__ pAhi, const u16* __restrict__ pAlo,
    float* __restrict__ pbufq, float* __restrict__ gbufq, int b0)
{
    __shared__ short8 BldsV[4096];           // 64 KB
    char* Blds = (char*)BldsV;
    int tid = threadIdx.x, lane = tid & 63, wid = tid >> 6;
    int wm = wid >> 1, wn = wid & 1;
    int pix0 = blockIdx.x * 128;
    int by   = blockIdx.y;                   // 0: p rows, 1: g rows
    int rt   = 2 + by;
    int bz = blockIdx.z, bg = b0 + bz;

    const char* srcHi = (const char*)(xThi + ((size_t)bg * 4096 + pix0) * 256);
    const char* srcLo = (const char*)(xTlo + ((size_t)bg * 4096 + pix0) * 256);

    f32x4 acc[4][4];
    #pragma unroll
    for (int m = 0; m < 4; ++m)
        #pragma unroll
        for (int n = 0; n < 4; ++n) acc[m][n] = (f32x4)0.0f;

    STAGE(srcHi);
    __syncthreads();
    MFMA_PASS(pAhi);
    MFMA_PASS(pAlo);
    __syncthreads();     // all waves done reading hi panel
    STAGE(srcLo);
    __syncthreads();
    MFMA_PASS(pAhi);

    float* dst = (by == 0) ? pbufq : gbufq;
    int colb = pix0 + wn * 64;
    int rowb = wm * 64;                  // 0..127 within p or g
    #pragma unroll
    for (int m = 0; m < 4; ++m)
        #pragma unroll
        for (int n = 0; n < 4; ++n)
            #pragma unroll
            for (int r = 0; r < 4; ++r) {
                int row = rowb + m * 16 + (lane >> 4) * 4 + r;
                int col = colb + n * 16 + (lane & 15);
                dst[((size_t)bz * 128 + row) * 4096 + col] = acc[m][n][r];
            }
}

// ---------------------------------------------------------------------------
// Kernel 3: attention dot (f32), quarter batch.  Block per (c, gi, bz).
// ---------------------------------------------------------------------------
__global__ __launch_bounds__(256) void k_att(
    const float* __restrict__ pbufq, const float* __restrict__ gbufq,
    float* __restrict__ att, int b0)
{
    __shared__ float plds[HW_];
    __shared__ float glds[HW_];
    __shared__ float scr[8];
    int c  = blockIdx.x;   // 0..31
    int gi = blockIdx.y;   // 0..3
    int bz = blockIdx.z;   // 0..3
    int tid = threadIdx.x;

    const float* pp = pbufq + ((size_t)bz * 128 + gi * 32 + c) * HW_;
    const float* gg = gbufq + ((size_t)bz * 128 + gi * 32 + c) * HW_;

    float racc = 0.0f;
    #pragma unroll
    for (int it = 0; it < 4; ++it) {
        int i = it * 1024 + tid * 4;
        float4 pv = *(const float4*)(pp + i);
        float4 gv = *(const float4*)(gg + i);
        *(float4*)(&plds[i]) = pv;
        *(float4*)(&glds[i]) = gv;
        racc += pv.x * gv.x + pv.y * gv.y + pv.z * gv.z + pv.w * gv.w;
    }
    __syncthreads();

    float pacc = 0.0f;
    #pragma unroll 4
    for (int i = tid; i < HW_; i += 256) {
        int h = i >> 6, w = i & 63;
        int h0 = max(h - 1, 0), h1 = min(h + 1, 63);
        int w0 = max(w - 1, 0), w1 = min(w + 1, 63);
        float mp = -3.0e38f, mg = -3.0e38f;
        for (int hh = h0; hh <= h1; ++hh)
            for (int ww = w0; ww <= w1; ++ww) {
                mp = fmaxf(mp, plds[hh * 64 + ww]);
                mg = fmaxf(mg, glds[hh * 64 + ww]);
            }
        pacc += mp * mg;
    }

    #pragma unroll
    for (int off = 32; off > 0; off >>= 1) {
        racc += __shfl_down(racc, off, 64);
        pacc += __shfl_down(pacc, off, 64);
    }
    int lane = tid & 63, wid = tid >> 6;
    if (lane == 0) { scr[wid] = racc; scr[4 + wid] = pacc; }
    __syncthreads();
    if (tid == 0) {
        int bg = b0 + bz;
        atomicAdd(&att[bg * 8 + gi],     scr[0] + scr[1] + scr[2] + scr[3]);
        atomicAdd(&att[bg * 8 + gi + 4], scr[4] + scr[5] + scr[6] + scr[7]);
    }
}

// ---------------------------------------------------------------------------
// Kernel 4: per-row softmax stats (bf16 input).  rowstat = (max, 1/expsum)
// ---------------------------------------------------------------------------
__global__ __launch_bounds__(256) void k_smax(
    const u16* __restrict__ tbuf, float2* __restrict__ rowstat)
{
    __shared__ float scr[8];
    int r = blockIdx.x;
    const u16* tr = tbuf + (size_t)r * HW_;
    int tid = threadIdx.x;
    int lane = tid & 63, wid = tid >> 6;

    float vals[16];
    float mx = -3.0e38f;
    #pragma unroll
    for (int it = 0; it < 2; ++it) {
        short8 v = *(const short8*)(tr + it * 2048 + tid * 8);
        #pragma unroll
        for (int j = 0; j < 8; ++j) {
            float f = bf2f((u16)v[j]);
            vals[it * 8 + j] = f;
            mx = fmaxf(mx, f);
        }
    }
    #pragma unroll
    for (int off = 32; off > 0; off >>= 1) mx = fmaxf(mx, __shfl_down(mx, off, 64));
    if (lane == 0) scr[wid] = mx;
    __syncthreads();
    if (tid == 0) scr[0] = fmaxf(fmaxf(scr[0], scr[1]), fmaxf(scr[2], scr[3]));
    __syncthreads();
    float m = scr[0];
    __syncthreads();

    float s = 0.0f;
    #pragma unroll
    for (int j = 0; j < 16; ++j) s += __expf(vals[j] - m);
    #pragma unroll
    for (int off = 32; off > 0; off >>= 1) s += __shfl_down(s, off, 64);
    if (lane == 0) scr[4 + wid] = s;
    __syncthreads();
    if (tid == 0) {
        float S = scr[4] + scr[5] + scr[6] + scr[7];
        rowstat[r] = make_float2(m, 1.0f / S);
    }
}

// ---------------------------------------------------------------------------
// Kernel 5: fused softmax-apply + xz mix + GN stats, in place over bf16 tbuf.
// Block per (pt 512px, gi, b); 2 px per thread; wz in 4 KB LDS.
// ---------------------------------------------------------------------------
__global__ __launch_bounds__(256) void k_xz2(
    u16* __restrict__ tbuf, const float* __restrict__ Wz,
    const float2* __restrict__ rowstat, const float* __restrict__ att,
    float* __restrict__ stats)
{
    __shared__ float wz[32][32];
    __shared__ float2 rs[32];
    __shared__ float scr[8];
    int pt  = blockIdx.x;   // 0..7  (512-pixel tile)
    int gi  = blockIdx.y;   // 0..7
    int b   = blockIdx.z;   // 0..15
    int tid = threadIdx.x;
    int px  = pt * 512 + tid * 2;

    const float* wzg = Wz + gi * 1024;
    #pragma unroll
    for (int i = 0; i < 4; ++i) {
        int idx = tid + i * 256;
        wz[idx >> 5][idx & 31] = wzg[idx];
    }
    if (tid < 32) rs[tid] = rowstat[b * 256 + gi * 32 + tid];
    __syncthreads();

    u16* base = tbuf + ((size_t)b * 256 + gi * 32) * HW_;
    float2 v[32];
    #pragma unroll
    for (int i = 0; i < 32; ++i) {
        unsigned rv = *(const unsigned*)(base + (size_t)i * HW_ + px);
        float m = rs[i].x, inv = rs[i].y;
        v[i].x = __expf(bf2f((u16)(rv & 0xffffu)) - m) * inv;
        v[i].y = __expf(bf2f((u16)(rv >> 16)) - m) * inv;
    }

    float a = att[b * 8 + gi];
    float s1 = 0.0f, s2 = 0.0f;
    #pragma unroll
    for (int o = 0; o < 32; ++o) {
        const float4* wzo = (const float4*)(&wz[o][0]);
        float ax = 0.0f, ay = 0.0f;
        #pragma unroll
        for (int j = 0; j < 8; ++j) {
            float4 w = wzo[j];
            ax = fmaf(w.x, v[4*j+0].x, ax); ay = fmaf(w.x, v[4*j+0].y, ay);
            ax = fmaf(w.y, v[4*j+1].x, ax); ay = fmaf(w.y, v[4*j+1].y, ay);
            ax = fmaf(w.z, v[4*j+2].x, ax); ay = fmaf(w.z, v[4*j+2].y, ay);
            ax = fmaf(w.w, v[4*j+3].x, ax); ay = fmaf(w.w, v[4*j+3].y, ay);
        }
        ax *= a; ay *= a;
        unsigned ov = (unsigned)f2bf(ax) | ((unsigned)f2bf(ay) << 16);
        *(unsigned*)(base + (size_t)o * HW_ + px) = ov;
        s1 += ax + ay;
        s2 = fmaf(ax, ax, fmaf(ay, ay, s2));
    }

    #pragma unroll
    for (int off = 32; off > 0; off >>= 1) {
        s1 += __shfl_down(s1, off, 64);
        s2 += __shfl_down(s2, off, 64);
    }
    int lane = tid & 63, wid = tid >> 6;
    if (lane == 0) { scr[wid] = s1; scr[4 + wid] = s2; }
    __syncthreads();
    if (tid == 0) {
        atomicAdd(&stats[(b * 8 + gi) * 2 + 0], scr[0] + scr[1] + scr[2] + scr[3]);
        atomicAdd(&stats[(b * 8 + gi) * 2 + 1], scr[4] + scr[5] + scr[6] + scr[7]);
    }
}

// ---------------------------------------------------------------------------
// Kernel 6: GroupNorm finalize + affine + residual (4 elems/thread)
// ---------------------------------------------------------------------------
__global__ __launch_bounds__(256) void k_finalize(
    const u16* __restrict__ xzbuf, const float* __restrict__ x,
    const float* __restrict__ stats, const float* __restrict__ gamma,
    const float* __restrict__ beta, float* __restrict__ out)
{
    size_t i0 = ((size_t)blockIdx.x * 256 + threadIdx.x) * 4;
    int c  = (int)((i0 >> 12) & 255);
    int bg = (int)(i0 >> 17);
    float s1 = stats[bg * 2], s2 = stats[bg * 2 + 1];
    const float invN = 1.0f / 131072.0f;
    float mu  = s1 * invN;
    float var = s2 * invN - mu * mu;
    float rs  = rsqrtf(var + EPSV);
    float ga = gamma[c], be = beta[c];

    union { unsigned long long u; u16 h[4]; } vv;
    vv.u = *(const unsigned long long*)(xzbuf + i0);
    float4 xv = *(const float4*)(x + i0);
    float4 o;
    o.x = (bf2f(vv.h[0]) - mu) * rs * ga + be + xv.x;
    o.y = (bf2f(vv.h[1]) - mu) * rs * ga + be + xv.y;
    o.z = (bf2f(vv.h[2]) - mu) * rs * ga + be + xv.z;
    o.w = (bf2f(vv.h[3]) - mu) * rs * ga + be + xv.w;
    *(float4*)(out + i0) = o;
}

// ---------------------------------------------------------------------------
extern "C" void kernel_launch(void* const* d_in, const int* in_sizes, int n_in,
                              void* d_out, int out_size, void* d_ws, size_t ws_size,
                              hipStream_t stream)
{
    const float* x     = (const float*)d_in[0];
    const float* mask  = (const float*)d_in[1];
    const float* Wt    = (const float*)d_in[2];
    const float* Wtm   = (const float*)d_in[3];
    const float* Wp    = (const float*)d_in[4];
    const float* Wg    = (const float*)d_in[5];
    const float* Wz    = (const float*)d_in[6];
    const float* gamma = (const float*)d_in[7];
    const float* beta  = (const float*)d_in[8];
    float* out = (float*)d_out;

    // workspace layout (bytes), total ~118.3 MB (< proven 128.3 MB):
    //   tbuf  (bf16, full batch): 33,554,432   (t -> xz in place)
    //   xThi / xTlo (bf16, FULL batch): 33,554,432 each
    //   pbufq / gbufq (f32, quarter batch): 8,388,608 each
    //   pAhi/pAlo: 262,144 each ; tmod (f32): 262,144
    //   att/stats: 1,536 ; rowstat (float2[4096]): 32,768
    char* ws = (char*)d_ws;
    u16*   tbuf  = (u16*)(ws);
    u16*   xThi  = (u16*)(ws + 33554432);
    u16*   xTlo  = (u16*)(ws + 67108864);
    float* pbufq = (float*)(ws + 100663296);
    float* gbufq = (float*)(ws + 109051904);
    u16*   pAhi  = (u16*)(ws + 117440512);
    u16*   pAlo  = (u16*)(ws + 117702656);
    float* tmod  = (float*)(ws + 117964800);
    float* att   = (float*)(ws + 118226944);
    float* stats = att + 128;
    float2* rowstat = (float2*)(ws + 118231040);

    k_packA    <<<64, 256, 0, stream>>>(Wt, Wp, Wg, pAhi, pAlo);
    k_tmod_zero<<<256, 256, 0, stream>>>(mask, Wtm, tmod, att, stats);
    k_transpose<<<dim3(32, 8, 16), 256, 0, stream>>>(x, xThi, xTlo);
    k_mm0      <<<dim3(32, 2, 16), 256, 0, stream>>>(xThi, pAhi, tmod, tbuf);
    for (int b0 = 0; b0 < 16; b0 += 4) {
        k_mm1<<<dim3(32, 2, 4), 256, 0, stream>>>(xThi, xTlo, pAhi, pAlo,
                                                  pbufq, gbufq, b0);
        k_att<<<dim3(32, 4, 4), 256, 0, stream>>>(pbufq, gbufq, att, b0);
    }
    k_smax     <<<4096, 256, 0, stream>>>(tbuf, rowstat);
    k_xz2      <<<dim3(8, 8, 16), 256, 0, stream>>>(tbuf, Wz, rowstat, att, stats);
    k_finalize <<<16384, 256, 0, stream>>>(tbuf, x, stats, gamma, beta, out);
}

// Round 9
// 216.616 us; speedup vs baseline: 3.3018x; 1.2688x over previous
//
#include <hip/hip_runtime.h>
#include <math.h>

#define B_      16
#define CIN     256
#define HW_     4096          // 64x64
#define PLANES  256
#define G_      8
#define EPSV    1e-5f

typedef unsigned short u16;
typedef __attribute__((ext_vector_type(8))) short short8;   // 8 bf16 (4 VGPRs)
typedef __attribute__((ext_vector_type(4))) float f32x4;    // MFMA acc

__device__ inline u16 f2bf(float f) {
    union { float f; unsigned u; } v; v.f = f;
    unsigned u = v.u;
    return (u16)((u + 0x7fffu + ((u >> 16) & 1u)) >> 16);   // RNE
}
__device__ inline float bf2f(u16 h) {
    union { unsigned u; float f; } v; v.u = ((unsigned)h) << 16;
    return v.f;
}

// ---------------------------------------------------------------------------
// Kernel 0a: pack Wt|Wp|Wg (512x256 f32) into MFMA A-fragment order, split
// into bf16 hi + lo (w = hi + lo, exact to ~2^-16 rel).
// slot (rt 0..3, kt 0..7, mb 0..7, lane 0..63, j 0..7):
//   row = rt*128 + mb*16 + (lane&15); k = kt*32 + (lane>>4)*8 + j
// ---------------------------------------------------------------------------
__global__ __launch_bounds__(256) void k_packA(
    const float* __restrict__ Wt, const float* __restrict__ Wp,
    const float* __restrict__ Wg,
    u16* __restrict__ pAhi, u16* __restrict__ pAlo)
{
    int t = blockIdx.x * 256 + threadIdx.x;      // 0..16383
    int lane = t & 63;
    int mb   = (t >> 6) & 7;
    int kt   = (t >> 9) & 7;
    int rt   = (t >> 12) & 3;
    int row = rt * 128 + mb * 16 + (lane & 15);
    int k0  = kt * 32 + (lane >> 4) * 8;
    const float* src;
    if      (row < 256) src = Wt + (size_t)row * 256;
    else if (row < 384) src = Wp + (size_t)(row - 256) * 256;
    else                src = Wg + (size_t)(row - 384) * 256;
    u16 hv[8], lv[8];
    #pragma unroll
    for (int j = 0; j < 8; ++j) {
        float w = src[k0 + j];
        u16 h = f2bf(w);
        hv[j] = h;
        lv[j] = f2bf(w - bf2f(h));
    }
    *(short8*)(pAhi + (size_t)t * 8) = *(short8*)hv;
    *(short8*)(pAlo + (size_t)t * 8) = *(short8*)lv;
}

// ---------------------------------------------------------------------------
// Kernel 0b: transpose x[b][256][4096] f32 -> xThi/xTlo[b][4096][256]
// bf16 hi/lo split.  FULL batch, one launch (4096 blocks).
// ---------------------------------------------------------------------------
__global__ __launch_bounds__(256) void k_transpose(
    const float* __restrict__ x, u16* __restrict__ xThi,
    u16* __restrict__ xTlo)
{
    __shared__ float tile[32][129];
    int tid = threadIdx.x;
    int px0 = blockIdx.x * 128;
    int c0  = blockIdx.y * 32;
    int bg  = blockIdx.z;

    #pragma unroll
    for (int it = 0; it < 16; ++it) {
        int flat = it * 256 + tid;
        int c_l = flat >> 7, p_l = flat & 127;
        tile[c_l][p_l] = x[((size_t)bg * 256 + c0 + c_l) * 4096 + px0 + p_l];
    }
    __syncthreads();
    #pragma unroll
    for (int it = 0; it < 8; ++it) {
        int flat = it * 256 + tid;          // 0..2047
        int p_l = flat >> 4;
        int c_l = (flat & 15) * 2;
        float v0 = tile[c_l][p_l], v1 = tile[c_l + 1][p_l];
        u16 h0 = f2bf(v0), h1 = f2bf(v1);
        u16 l0 = f2bf(v0 - bf2f(h0)), l1 = f2bf(v1 - bf2f(h1));
        size_t o = ((size_t)bg * 4096 + px0 + p_l) * 256 + c0 + c_l;
        u16 ho[2] = { h0, h1 };
        u16 lo[2] = { l0, l1 };
        *(unsigned*)(xThi + o) = *(unsigned*)ho;
        *(unsigned*)(xTlo + o) = *(unsigned*)lo;
    }
}

// ---------------------------------------------------------------------------
// Kernel 1: tmod + zero att/stats
// ---------------------------------------------------------------------------
__global__ __launch_bounds__(256) void k_tmod_zero(
    const float* __restrict__ mask, const float* __restrict__ Wtm,
    float* __restrict__ tmod, float* __restrict__ att, float* __restrict__ stats)
{
    int idx = blockIdx.x * 256 + threadIdx.x;
    float w0 = Wtm[0], w1 = Wtm[1];
    if (idx < B_ * HW_) {
        int b = idx >> 12, pix = idx & 4095;
        const float* mb = mask + (size_t)b * 2 * HW_;
        tmod[idx] = 1.0f + w0 * mb[pix] + w1 * mb[HW_ + pix];
    }
    if (blockIdx.x == 0) {
        if (threadIdx.x < 128) att[threadIdx.x] = 0.0f;
        stats[threadIdx.x] = 0.0f;
    }
}

// ---------------------------------------------------------------------------
// Shared GEMM building blocks.  Block: 128 rows x 128 px, 4 waves (2x2).
// 64 KB LDS B-panel, XOR-swizzled.
// ---------------------------------------------------------------------------
#define STAGE(SRC)                                                            \
    _Pragma("unroll")                                                         \
    for (int it = 0; it < 16; ++it) {                                         \
        int cidx = it * 256 + tid;                                            \
        int px   = cidx >> 5;                                                 \
        int boff = (cidx & 31) << 4;                                          \
        short8 v = *(const short8*)((SRC) + (size_t)px * 512 + boff);         \
        *(short8*)(Blds + px * 512 + (boff ^ ((px & 7) << 4))) = v;           \
    }

#define MFMA_PASS(ASRC)                                                       \
    _Pragma("unroll")                                                         \
    for (int kt = 0; kt < 8; ++kt) {                                          \
        short8 a[4], bb[4];                                                   \
        _Pragma("unroll")                                                     \
        for (int m = 0; m < 4; ++m)                                           \
            a[m] = *(const short8*)((ASRC) +                                  \
                ((((size_t)(rt * 8 + kt) * 8) + wm * 4 + m) * 64 + lane) * 8);\
        int off = ((kt * 64) + ((lane >> 4) << 4)) ^ ((lane & 7) << 4);       \
        _Pragma("unroll")                                                     \
        for (int n = 0; n < 4; ++n) {                                         \
            int px = wn * 64 + n * 16 + (lane & 15);                          \
            bb[n] = *(const short8*)(Blds + px * 512 + off);                  \
        }                                                                     \
        _Pragma("unroll")                                                     \
        for (int m = 0; m < 4; ++m)                                           \
            _Pragma("unroll")                                                 \
            for (int n = 0; n < 4; ++n)                                       \
                acc[m][n] = __builtin_amdgcn_mfma_f32_16x16x32_bf16(          \
                    a[m], bb[n], acc[m][n], 0, 0, 0);                         \
    }

// ---------------------------------------------------------------------------
// Kernel 2a: t-GEMM, FULL batch, 1 bf16 pass -> bf16 tbuf (* tmod).
// Grid (32 px-tiles, 2 row-tiles, 16 b) = 1024 blocks.
// ---------------------------------------------------------------------------
__global__ __launch_bounds__(256) void k_mm0(
    const u16* __restrict__ xThi, const u16* __restrict__ pAhi,
    const float* __restrict__ tmod, u16* __restrict__ tbuf)
{
    __shared__ short8 BldsV[4096];           // 64 KB
    char* Blds = (char*)BldsV;
    int tid = threadIdx.x, lane = tid & 63, wid = tid >> 6;
    int wm = wid >> 1, wn = wid & 1;
    int pix0 = blockIdx.x * 128;
    int rt   = blockIdx.y;                   // 0..1 (t rows)
    int bg   = blockIdx.z;

    const char* srcHi = (const char*)(xThi + ((size_t)bg * 4096 + pix0) * 256);

    f32x4 acc[4][4];
    #pragma unroll
    for (int m = 0; m < 4; ++m)
        #pragma unroll
        for (int n = 0; n < 4; ++n) acc[m][n] = (f32x4)0.0f;

    STAGE(srcHi);
    __syncthreads();
    MFMA_PASS(pAhi);

    int colb = pix0 + wn * 64;
    int rowb = rt * 128 + wm * 64;
    float tm[4];
    #pragma unroll
    for (int n = 0; n < 4; ++n) tm[n] = tmod[bg * 4096 + colb + n * 16 + (lane & 15)];
    #pragma unroll
    for (int m = 0; m < 4; ++m)
        #pragma unroll
        for (int n = 0; n < 4; ++n)
            #pragma unroll
            for (int r = 0; r < 4; ++r) {
                int row = rowb + m * 16 + (lane >> 4) * 4 + r;
                int col = colb + n * 16 + (lane & 15);
                tbuf[((size_t)bg * 256 + row) * 4096 + col] = f2bf(acc[m][n][r] * tm[n]);
            }
}

// ---------------------------------------------------------------------------
// Kernel 2b: p/g-GEMM, FULL batch, 3 passes (f32-exact) -> f32 pbuf/gbuf.
// Grid (32 px-tiles, 2 {p,g}, 16 b) = 1024 blocks.
// ---------------------------------------------------------------------------
__global__ __launch_bounds__(256) void k_mm1(
    const u16* __restrict__ xThi, const u16* __restrict__ xTlo,
    const u16* __restrict__ pAhi, const u16* __restrict__ pAlo,
    float* __restrict__ pbuf, float* __restrict__ gbuf)
{
    __shared__ short8 BldsV[4096];           // 64 KB
    char* Blds = (char*)BldsV;
    int tid = threadIdx.x, lane = tid & 63, wid = tid >> 6;
    int wm = wid >> 1, wn = wid & 1;
    int pix0 = blockIdx.x * 128;
    int by   = blockIdx.y;                   // 0: p rows, 1: g rows
    int rt   = 2 + by;
    int bg   = blockIdx.z;

    const char* srcHi = (const char*)(xThi + ((size_t)bg * 4096 + pix0) * 256);
    const char* srcLo = (const char*)(xTlo + ((size_t)bg * 4096 + pix0) * 256);

    f32x4 acc[4][4];
    #pragma unroll
    for (int m = 0; m < 4; ++m)
        #pragma unroll
        for (int n = 0; n < 4; ++n) acc[m][n] = (f32x4)0.0f;

    STAGE(srcHi);
    __syncthreads();
    MFMA_PASS(pAhi);
    MFMA_PASS(pAlo);
    __syncthreads();     // all waves done reading hi panel
    STAGE(srcLo);
    __syncthreads();
    MFMA_PASS(pAhi);

    float* dst = (by == 0) ? pbuf : gbuf;
    int colb = pix0 + wn * 64;
    int rowb = wm * 64;                  // 0..127 within p or g
    #pragma unroll
    for (int m = 0; m < 4; ++m)
        #pragma unroll
        for (int n = 0; n < 4; ++n)
            #pragma unroll
            for (int r = 0; r < 4; ++r) {
                int row = rowb + m * 16 + (lane >> 4) * 4 + r;
                int col = colb + n * 16 + (lane & 15);
                dst[((size_t)bg * 128 + row) * 4096 + col] = acc[m][n][r];
            }
}

// ---------------------------------------------------------------------------
// Kernel 3: attention dot (f32), FULL batch.  Block per (c, gi, b).
// ---------------------------------------------------------------------------
__global__ __launch_bounds__(256) void k_att(
    const float* __restrict__ pbuf, const float* __restrict__ gbuf,
    float* __restrict__ att)
{
    __shared__ float plds[HW_];
    __shared__ float glds[HW_];
    __shared__ float scr[8];
    int c  = blockIdx.x;   // 0..31
    int gi = blockIdx.y;   // 0..3
    int b  = blockIdx.z;   // 0..15
    int tid = threadIdx.x;

    const float* pp = pbuf + ((size_t)b * 128 + gi * 32 + c) * HW_;
    const float* gg = gbuf + ((size_t)b * 128 + gi * 32 + c) * HW_;

    float racc = 0.0f;
    #pragma unroll
    for (int it = 0; it < 4; ++it) {
        int i = it * 1024 + tid * 4;
        float4 pv = *(const float4*)(pp + i);
        float4 gv = *(const float4*)(gg + i);
        *(float4*)(&plds[i]) = pv;
        *(float4*)(&glds[i]) = gv;
        racc += pv.x * gv.x + pv.y * gv.y + pv.z * gv.z + pv.w * gv.w;
    }
    __syncthreads();

    float pacc = 0.0f;
    #pragma unroll 4
    for (int i = tid; i < HW_; i += 256) {
        int h = i >> 6, w = i & 63;
        int h0 = max(h - 1, 0), h1 = min(h + 1, 63);
        int w0 = max(w - 1, 0), w1 = min(w + 1, 63);
        float mp = -3.0e38f, mg = -3.0e38f;
        for (int hh = h0; hh <= h1; ++hh)
            for (int ww = w0; ww <= w1; ++ww) {
                mp = fmaxf(mp, plds[hh * 64 + ww]);
                mg = fmaxf(mg, glds[hh * 64 + ww]);
            }
        pacc += mp * mg;
    }

    #pragma unroll
    for (int off = 32; off > 0; off >>= 1) {
        racc += __shfl_down(racc, off, 64);
        pacc += __shfl_down(pacc, off, 64);
    }
    int lane = tid & 63, wid = tid >> 6;
    if (lane == 0) { scr[wid] = racc; scr[4 + wid] = pacc; }
    __syncthreads();
    if (tid == 0) {
        atomicAdd(&att[b * 8 + gi],     scr[0] + scr[1] + scr[2] + scr[3]);
        atomicAdd(&att[b * 8 + gi + 4], scr[4] + scr[5] + scr[6] + scr[7]);
    }
}

// ---------------------------------------------------------------------------
// Kernel 4: per-row softmax stats (bf16 input).  rowstat = (max, 1/expsum)
// ---------------------------------------------------------------------------
__global__ __launch_bounds__(256) void k_smax(
    const u16* __restrict__ tbuf, float2* __restrict__ rowstat)
{
    __shared__ float scr[8];
    int r = blockIdx.x;
    const u16* tr = tbuf + (size_t)r * HW_;
    int tid = threadIdx.x;
    int lane = tid & 63, wid = tid >> 6;

    float vals[16];
    float mx = -3.0e38f;
    #pragma unroll
    for (int it = 0; it < 2; ++it) {
        short8 v = *(const short8*)(tr + it * 2048 + tid * 8);
        #pragma unroll
        for (int j = 0; j < 8; ++j) {
            float f = bf2f((u16)v[j]);
            vals[it * 8 + j] = f;
            mx = fmaxf(mx, f);
        }
    }
    #pragma unroll
    for (int off = 32; off > 0; off >>= 1) mx = fmaxf(mx, __shfl_down(mx, off, 64));
    if (lane == 0) scr[wid] = mx;
    __syncthreads();
    if (tid == 0) scr[0] = fmaxf(fmaxf(scr[0], scr[1]), fmaxf(scr[2], scr[3]));
    __syncthreads();
    float m = scr[0];
    __syncthreads();

    float s = 0.0f;
    #pragma unroll
    for (int j = 0; j < 16; ++j) s += __expf(vals[j] - m);
    #pragma unroll
    for (int off = 32; off > 0; off >>= 1) s += __shfl_down(s, off, 64);
    if (lane == 0) scr[4 + wid] = s;
    __syncthreads();
    if (tid == 0) {
        float S = scr[4] + scr[5] + scr[6] + scr[7];
        rowstat[r] = make_float2(m, 1.0f / S);
    }
}

// ---------------------------------------------------------------------------
// Kernel 5: fused softmax-apply + xz mix + GN stats, in place over bf16 tbuf.
// Block per (pt 512px, gi, b); 2 px per thread; wz in 4 KB LDS.
// ---------------------------------------------------------------------------
__global__ __launch_bounds__(256) void k_xz2(
    u16* __restrict__ tbuf, const float* __restrict__ Wz,
    const float2* __restrict__ rowstat, const float* __restrict__ att,
    float* __restrict__ stats)
{
    __shared__ float wz[32][32];
    __shared__ float2 rs[32];
    __shared__ float scr[8];
    int pt  = blockIdx.x;   // 0..7  (512-pixel tile)
    int gi  = blockIdx.y;   // 0..7
    int b   = blockIdx.z;   // 0..15
    int tid = threadIdx.x;
    int px  = pt * 512 + tid * 2;

    const float* wzg = Wz + gi * 1024;
    #pragma unroll
    for (int i = 0; i < 4; ++i) {
        int idx = tid + i * 256;
        wz[idx >> 5][idx & 31] = wzg[idx];
    }
    if (tid < 32) rs[tid] = rowstat[b * 256 + gi * 32 + tid];
    __syncthreads();

    u16* base = tbuf + ((size_t)b * 256 + gi * 32) * HW_;
    float2 v[32];
    #pragma unroll
    for (int i = 0; i < 32; ++i) {
        unsigned rv = *(const unsigned*)(base + (size_t)i * HW_ + px);
        float m = rs[i].x, inv = rs[i].y;
        v[i].x = __expf(bf2f((u16)(rv & 0xffffu)) - m) * inv;
        v[i].y = __expf(bf2f((u16)(rv >> 16)) - m) * inv;
    }

    float a = att[b * 8 + gi];
    float s1 = 0.0f, s2 = 0.0f;
    #pragma unroll
    for (int o = 0; o < 32; ++o) {
        const float4* wzo = (const float4*)(&wz[o][0]);
        float ax = 0.0f, ay = 0.0f;
        #pragma unroll
        for (int j = 0; j < 8; ++j) {
            float4 w = wzo[j];
            ax = fmaf(w.x, v[4*j+0].x, ax); ay = fmaf(w.x, v[4*j+0].y, ay);
            ax = fmaf(w.y, v[4*j+1].x, ax); ay = fmaf(w.y, v[4*j+1].y, ay);
            ax = fmaf(w.z, v[4*j+2].x, ax); ay = fmaf(w.z, v[4*j+2].y, ay);
            ax = fmaf(w.w, v[4*j+3].x, ax); ay = fmaf(w.w, v[4*j+3].y, ay);
        }
        ax *= a; ay *= a;
        unsigned ov = (unsigned)f2bf(ax) | ((unsigned)f2bf(ay) << 16);
        *(unsigned*)(base + (size_t)o * HW_ + px) = ov;
        s1 += ax + ay;
        s2 = fmaf(ax, ax, fmaf(ay, ay, s2));
    }

    #pragma unroll
    for (int off = 32; off > 0; off >>= 1) {
        s1 += __shfl_down(s1, off, 64);
        s2 += __shfl_down(s2, off, 64);
    }
    int lane = tid & 63, wid = tid >> 6;
    if (lane == 0) { scr[wid] = s1; scr[4 + wid] = s2; }
    __syncthreads();
    if (tid == 0) {
        atomicAdd(&stats[(b * 8 + gi) * 2 + 0], scr[0] + scr[1] + scr[2] + scr[3]);
        atomicAdd(&stats[(b * 8 + gi) * 2 + 1], scr[4] + scr[5] + scr[6] + scr[7]);
    }
}

// ---------------------------------------------------------------------------
// Kernel 6: GroupNorm finalize + affine + residual (4 elems/thread)
// ---------------------------------------------------------------------------
__global__ __launch_bounds__(256) void k_finalize(
    const u16* __restrict__ xzbuf, const float* __restrict__ x,
    const float* __restrict__ stats, const float* __restrict__ gamma,
    const float* __restrict__ beta, float* __restrict__ out)
{
    size_t i0 = ((size_t)blockIdx.x * 256 + threadIdx.x) * 4;
    int c  = (int)((i0 >> 12) & 255);
    int bg = (int)(i0 >> 17);
    float s1 = stats[bg * 2], s2 = stats[bg * 2 + 1];
    const float invN = 1.0f / 131072.0f;
    float mu  = s1 * invN;
    float var = s2 * invN - mu * mu;
    float rs  = rsqrtf(var + EPSV);
    float ga = gamma[c], be = beta[c];

    union { unsigned long long u; u16 h[4]; } vv;
    vv.u = *(const unsigned long long*)(xzbuf + i0);
    float4 xv = *(const float4*)(x + i0);
    float4 o;
    o.x = (bf2f(vv.h[0]) - mu) * rs * ga + be + xv.x;
    o.y = (bf2f(vv.h[1]) - mu) * rs * ga + be + xv.y;
    o.z = (bf2f(vv.h[2]) - mu) * rs * ga + be + xv.z;
    o.w = (bf2f(vv.h[3]) - mu) * rs * ga + be + xv.w;
    *(float4*)(out + i0) = o;
}

// ---------------------------------------------------------------------------
extern "C" void kernel_launch(void* const* d_in, const int* in_sizes, int n_in,
                              void* d_out, int out_size, void* d_ws, size_t ws_size,
                              hipStream_t stream)
{
    const float* x     = (const float*)d_in[0];
    const float* mask  = (const float*)d_in[1];
    const float* Wt    = (const float*)d_in[2];
    const float* Wtm   = (const float*)d_in[3];
    const float* Wp    = (const float*)d_in[4];
    const float* Wg    = (const float*)d_in[5];
    const float* Wz    = (const float*)d_in[6];
    const float* gamma = (const float*)d_in[7];
    const float* beta  = (const float*)d_in[8];
    float* out = (float*)d_out;

    // workspace layout (bytes), total ~235.7 MB (ws_size = 256 MiB per the
    // harness's 2.685e8-byte poison fill):
    //   tbuf  (bf16, full batch): 33,554,432   (t -> xz in place)
    //   xThi / xTlo (bf16, full batch): 33,554,432 each
    //   pbuf / gbuf (f32, FULL batch): 67,108,864 each
    //   pAhi/pAlo: 262,144 each ; tmod (f32): 262,144
    //   att/stats: 1,536 ; rowstat (float2[4096]): 32,768
    char* ws = (char*)d_ws;
    u16*   tbuf  = (u16*)(ws);
    u16*   xThi  = (u16*)(ws + 33554432);
    u16*   xTlo  = (u16*)(ws + 67108864);
    float* pbuf  = (float*)(ws + 100663296);
    float* gbuf  = (float*)(ws + 167772160);
    u16*   pAhi  = (u16*)(ws + 234881024);
    u16*   pAlo  = (u16*)(ws + 235143168);
    float* tmod  = (float*)(ws + 235405312);
    float* att   = (float*)(ws + 235667456);
    float* stats = att + 128;
    float2* rowstat = (float2*)(ws + 235669504);

    k_packA    <<<64, 256, 0, stream>>>(Wt, Wp, Wg, pAhi, pAlo);
    k_tmod_zero<<<256, 256, 0, stream>>>(mask, Wtm, tmod, att, stats);
    k_transpose<<<dim3(32, 8, 16), 256, 0, stream>>>(x, xThi, xTlo);
    k_mm0      <<<dim3(32, 2, 16), 256, 0, stream>>>(xThi, pAhi, tmod, tbuf);
    k_mm1      <<<dim3(32, 2, 16), 256, 0, stream>>>(xThi, xTlo, pAhi, pAlo, pbuf, gbuf);
    k_att      <<<dim3(32, 4, 16), 256, 0, stream>>>(pbuf, gbuf, att);
    k_smax     <<<4096, 256, 0, stream>>>(tbuf, rowstat);
    k_xz2      <<<dim3(8, 8, 16), 256, 0, stream>>>(tbuf, Wz, rowstat, att, stats);
    k_finalize <<<16384, 256, 0, stream>>>(tbuf, x, stats, gamma, beta, out);
}